// Round 13
// baseline (121.854 us; speedup 1.0000x reference)
//
#include <hip/hip_runtime.h>
#include <math.h>
#include <stdint.h>

// B=4, NQ=8192, NKV=8192, D=256, H=8, HD=32, KP=256. ROWS = 32768.
// Round-9 config (best: 83.9 us) + {p_buf b64 writes, reduce fused into
// lowproj2 (5 launches)}.
// L1 k_prep_all: x2,E,F -> xt fp16 [3][256][8192] (transposed); W transposes
// L2 k_mega1:    qgemm (512 blks): Qf = x1@Wq^T (B-frag layout)
//                + etx2 (128 blks): part = E^T x2 / F^T x2 (fp16 MFMA splitK16)
// L3 k_lowproj2: fused {reduce 16 partials} + {klow=G@Wk, vlow=Hh@Wv} ->
//                klowA/vtb direct
// L4 k_attn:     per (256-row tile, head): St=mfma(klow,Q), exp2 softmax,
//                PV -> O bf16 (2 row-subtiles per staged KV)
// L5 k_ogemm:    out = O @ Wo^T (f32)

typedef unsigned short ushort_t;
typedef __attribute__((ext_vector_type(8))) short bf16x8;
typedef __attribute__((ext_vector_type(8))) _Float16 f16x8;
typedef __attribute__((ext_vector_type(4))) float f32x4;

__device__ __forceinline__ f32x4 MFMA(bf16x8 a, bf16x8 b, f32x4 c) {
  return __builtin_amdgcn_mfma_f32_16x16x32_bf16(a, b, c, 0, 0, 0);
}
__device__ __forceinline__ f32x4 MFMA_H(f16x8 a, f16x8 b, f32x4 c) {
  return __builtin_amdgcn_mfma_f32_16x16x32_f16(a, b, c, 0, 0, 0);
}
__device__ __forceinline__ ushort_t f2bf(float x) {
  uint32_t u = __float_as_uint(x);
  u += 0x7fffu + ((u >> 16) & 1u);
  return (ushort_t)(u >> 16);
}
// packed f32 pair -> bf16x2 in one VALU op (lo = a, hi = b)
__device__ __forceinline__ uint32_t cvt_pk_bf16(float a, float b) {
  uint32_t r;
  asm("v_cvt_pk_bf16_f32 %0, %1, %2" : "=v"(r) : "v"(a), "v"(b));
  return r;
}
#define GLDS(gsrc, ldst)                                                    \
  __builtin_amdgcn_global_load_lds(                                         \
      (const __attribute__((address_space(1))) uint32_t*)(const void*)(gsrc), \
      (__attribute__((address_space(3))) uint32_t*)(void*)(ldst), 16, 0, 0)

// 3-bit XOR chunk staging helpers (proven rounds 3-9)
#define STAGE_ROW(u) \
  (((((u) >> 2) ^ ((u) >> 4)) & 1) | (((u) >> 2) & 6) | (((u) >> 5) << 3))
#define STAGE_G(u) \
  ((((u) ^ ((u) >> 2) ^ ((u) >> 4)) & 1) | (((((u) >> 1) ^ ((u) >> 3)) & 1) << 1))

// ---------------------------------------------------------------------------
// L1: transposes. grid (128,4,4), 256 thr. (unchanged, proven)
__global__ __launch_bounds__(256) void k_prep_all(
    const float* __restrict__ x2, const float* __restrict__ E,
    const float* __restrict__ F, const float* __restrict__ Wq,
    const float* __restrict__ Wk, const float* __restrict__ Wv,
    const float* __restrict__ Wo, _Float16* __restrict__ xt,
    ushort_t* __restrict__ wqt, ushort_t* __restrict__ wot,
    _Float16* __restrict__ wkt, _Float16* __restrict__ wvt) {
  __shared__ float tile[64][65];
  const int t = threadIdx.x;
  const int z = blockIdx.z;
  if (z < 3) {
    const int n0 = blockIdx.x * 64;
    const int c0 = blockIdx.y * 64;
    const float* __restrict__ src = (z == 0) ? x2 : (z == 1) ? E : F;
    _Float16* __restrict__ dst = xt + (size_t)z * 2097152;
    const int rr = t >> 4, cc = (t & 15) * 4;
#pragma unroll
    for (int i = 0; i < 4; ++i) {
      float4 v = *(const float4*)&src[(size_t)(n0 + rr + 16 * i) * 256 + c0 + cc];
      tile[cc + 0][rr + 16 * i] = v.x;
      tile[cc + 1][rr + 16 * i] = v.y;
      tile[cc + 2][rr + 16 * i] = v.z;
      tile[cc + 3][rr + 16 * i] = v.w;
    }
    __syncthreads();
#pragma unroll
    for (int rnd = 0; rnd < 2; ++rnd) {
      const int u = rnd * 256 + t;
      const int c = u >> 3, r0 = (u & 7) * 8;
      f16x8 h;
#pragma unroll
      for (int j = 0; j < 8; ++j) h[j] = (_Float16)tile[c][r0 + j];
      *(f16x8*)&dst[(size_t)(c0 + c) * 8192 + n0 + r0] = h;
    }
  } else {
    if (blockIdx.x >= 16) return;
    const int m = blockIdx.y;
    const float* __restrict__ src = (m == 0) ? Wq : (m == 1) ? Wo
                                  : (m == 2) ? Wk : Wv;
    const int tr = (blockIdx.x >> 2) * 64;
    const int tc = (blockIdx.x & 3) * 64;
    const int rr = t >> 4, cc = (t & 15) * 4;
#pragma unroll
    for (int i = 0; i < 4; ++i) {
      float4 v = *(const float4*)&src[(size_t)(tr + rr + 16 * i) * 256 + tc + cc];
      tile[cc + 0][rr + 16 * i] = v.x;
      tile[cc + 1][rr + 16 * i] = v.y;
      tile[cc + 2][rr + 16 * i] = v.z;
      tile[cc + 3][rr + 16 * i] = v.w;
    }
    __syncthreads();
#pragma unroll
    for (int rnd = 0; rnd < 2; ++rnd) {
      const int u = rnd * 256 + t;
      const int nl = u >> 3, kl = (u & 7) * 8;
      if (m < 2) {
        const float sc = (m == 0) ? 0.25503488f : 1.0f;  // scale*log2e
        bf16x8 hv;
#pragma unroll
        for (int j = 0; j < 8; ++j) hv[j] = (short)f2bf(tile[nl][kl + j] * sc);
        ushort_t* dst = (m == 0) ? wqt : wot;
        *(bf16x8*)&dst[(size_t)(tc + nl) * 256 + tr + kl] = hv;
      } else {
        f16x8 hv;
#pragma unroll
        for (int j = 0; j < 8; ++j) hv[j] = (_Float16)tile[nl][kl + j];
        _Float16* dst = (m == 2) ? wkt : wvt;
        *(f16x8*)&dst[(size_t)(tc + nl) * 256 + tr + kl] = hv;
      }
    }
  }
}

// ---------------------------------------------------------------------------
// L2: merged qgemm (bid<512) + etx2 (bid>=512, splitK16). grid 640, 256 thr.
__global__ __launch_bounds__(256, 3) void k_mega1(
    const float* __restrict__ x1, const _Float16* __restrict__ xt,
    const ushort_t* __restrict__ wqt, ushort_t* __restrict__ Qf,
    float* __restrict__ part) {
  __shared__ __align__(16) char smem[32768];
  const int t = threadIdx.x;
  const int wv = t >> 6, ln = t & 63;
  const int l15 = ln & 15, g = ln >> 4;

  if (blockIdx.x < 512) {
    // ---------------- qgemm: Qf = x1 @ wqt^T (B-frag layout) ----------------
    ushort_t* wstage = (ushort_t*)smem;
    const size_t r0 = (size_t)blockIdx.x * 64;
    auto stage = [&](int row0, int colu, int buf) {
#pragma unroll
      for (int rnd = 0; rnd < 2; ++rnd) {
        const int u = rnd * 256 + wv * 64 + ln;
        const int row = STAGE_ROW(u);
        const int gg = STAGE_G(u);
        GLDS(wqt + (size_t)(row0 + row) * 256 + colu + gg * 8,
             &wstage[(buf * 512 + rnd * 256 + wv * 64) * 8]);
      }
    };
    f32x4 qacc[16];
#pragma unroll
    for (int i = 0; i < 16; ++i) qacc[i] = {0.f, 0.f, 0.f, 0.f};
    stage(0, 0, 0);
    const float* xrow = x1 + (r0 + wv * 16 + l15) * 256;
    float4 xa = *(const float4*)(xrow + g * 8);
    float4 xb = *(const float4*)(xrow + g * 8 + 4);
    __syncthreads();
    for (int ci = 0; ci < 16; ++ci) {
      const int nh = ci & 1;
      if (ci < 15) stage(((ci + 1) & 1) * 128, ((ci + 1) >> 1) * 32, (ci + 1) & 1);
      union { uint32_t u[4]; bf16x8 v; } af;
      af.u[0] = cvt_pk_bf16(xa.x, xa.y);
      af.u[1] = cvt_pk_bf16(xa.z, xa.w);
      af.u[2] = cvt_pk_bf16(xb.x, xb.y);
      af.u[3] = cvt_pk_bf16(xb.z, xb.w);
      const bf16x8 afrag = af.v;
      const ushort_t* cw = &wstage[(ci & 1) * 4096];
#pragma unroll
      for (int tt = 0; tt < 8; ++tt) {
        bf16x8 bfr = *(const bf16x8*)&cw[((tt * 16 + l15) * 32 + g * 8) ^
                                         ((l15 & 7) << 3)];
        qacc[nh * 8 + tt] = MFMA(afrag, bfr, qacc[nh * 8 + tt]);
      }
      if (nh == 1 && ci < 15) {
        int ks = (ci >> 1) + 1;
        xa = *(const float4*)(xrow + ks * 32 + g * 8);
        xb = *(const float4*)(xrow + ks * 32 + g * 8 + 4);
      }
      __syncthreads();
    }
    char* myq = smem + wv * 8192;
#pragma unroll
    for (int tt = 0; tt < 16; ++tt)
#pragma unroll
      for (int r = 0; r < 4; ++r) {
        const int gr = g * 4 + r;
        *(ushort_t*)(myq + gr * 512 + (((tt * 16 + l15) * 2) ^ ((gr & 7) << 4))) =
            f2bf(qacc[tt][r]);
      }
    __builtin_amdgcn_sched_barrier(0);
    const int rt = blockIdx.x * 4 + wv;
#pragma unroll
    for (int hh = 0; hh < 8; ++hh) {
      bf16x8 qf = *(const bf16x8*)(myq + l15 * 512 +
                                   ((hh * 64 + g * 16) ^ ((l15 & 7) << 4)));
      *(bf16x8*)&Qf[((size_t)(rt * 8 + hh) * 64 + ln) * 8] = qf;
    }
  } else {
    // ---------------- etx2: part = E^T x2 / F^T x2 (splitK 16) --------------
    const int bid = blockIdx.x - 512;  // 0..127
    const int which = bid & 1;
    const int chunk = (bid >> 1) & 15;
    const int quad = bid >> 5;  // 0..3
    const int kp0 = (quad >> 1) * 128;
    const int d0 = (quad & 1) * 128;
    const int n0 = chunk * 512;
    const _Float16* __restrict__ A = xt + (size_t)(1 + which) * 2097152;
    const _Float16* __restrict__ B = xt;
    const int wr = wv >> 1, wc = wv & 1;
    f32x4 acc[4][4];
#pragma unroll
    for (int i = 0; i < 4; ++i)
#pragma unroll
      for (int j = 0; j < 4; ++j) acc[i][j] = {0.f, 0.f, 0.f, 0.f};

    for (int ks = 0; ks < 8; ++ks) {
#pragma unroll
      for (int r8 = 0; r8 < 8; ++r8) {
        const int u = r8 * 256 + t;      // 0..2047 16B units
        const int mm = u >> 10;          // 0:A 1:B
        const int uu = u & 1023;
        const int row = uu >> 3;
        const int nsw = ((uu ^ row) & 7) << 3;  // source-swizzled n-elems
        const _Float16* gs =
            (mm ? B + (size_t)(d0 + row) * 8192
                : A + (size_t)(kp0 + row) * 8192) +
            n0 + ks * 64 + nsw;
        GLDS(gs, smem + (u & ~63) * 16);
      }
      __syncthreads();
      const char* la = smem;
      const char* lb = smem + 16384;
#pragma unroll
      for (int kk = 0; kk < 2; ++kk) {
        f16x8 af[4], bf[4];
#pragma unroll
        for (int i = 0; i < 4; ++i) {
          const int ra = wr * 64 + i * 16 + l15;
          af[i] = *(const f16x8*)(la + ra * 128 +
                                  ((kk * 64 + g * 16) ^ ((ra & 7) << 4)));
        }
#pragma unroll
        for (int j = 0; j < 4; ++j) {
          const int rb = wc * 64 + j * 16 + l15;
          bf[j] = *(const f16x8*)(lb + rb * 128 +
                                  ((kk * 64 + g * 16) ^ ((rb & 7) << 4)));
        }
#pragma unroll
        for (int i = 0; i < 4; ++i)
#pragma unroll
          for (int j = 0; j < 4; ++j)
            acc[i][j] = MFMA_H(af[i], bf[j], acc[i][j]);
      }
      __syncthreads();
    }
    float* __restrict__ p = part + ((size_t)which * 16 + chunk) * 65536;
#pragma unroll
    for (int i = 0; i < 4; ++i)
#pragma unroll
      for (int j = 0; j < 4; ++j)
#pragma unroll
        for (int r = 0; r < 4; ++r)
          p[(size_t)(kp0 + wr * 64 + i * 16 + g * 4 + r) * 256 + d0 + wc * 64 +
            j * 16 + l15] = acc[i][j][r];
  }
}

// ---------------------------------------------------------------------------
// L3: FUSED {reduce 16 partials} + {klow/vlow proj}. grid (4,2), 256 thr.
// Phase 0: a_lds[64][256] fp16 (XOR-swz) = sum_c part[c][r0..r0+64][:].
// Phase 1: r9 lowproj main loop with A-frags from a_lds.
__global__ __launch_bounds__(256, 2) void k_lowproj2(
    const float* __restrict__ part, const _Float16* __restrict__ wkt,
    const _Float16* __restrict__ wvt, ushort_t* __restrict__ klowA,
    ushort_t* __restrict__ vtb) {
  __shared__ __align__(16) _Float16 a_lds[16384];     // 32 KB
  __shared__ __align__(16) _Float16 wstage[2][4096];  // 16 KB
  const int t = threadIdx.x;
  const int wv = t >> 6, ln = t & 63;
  const int l15 = ln & 15, g = ln >> 4;
  const int which = blockIdx.y;
  const int r0 = blockIdx.x * 64;
  const float* __restrict__ P = part + (size_t)which * 16 * 65536;
  const _Float16* __restrict__ W = which ? wvt : wkt;

  auto stage = [&](int row0, int colu, int buf) {
#pragma unroll
    for (int rnd = 0; rnd < 2; ++rnd) {
      const int u = rnd * 256 + wv * 64 + ln;
      const int row = STAGE_ROW(u);
      const int gg = STAGE_G(u);
      GLDS(W + (size_t)(row0 + row) * 256 + colu + gg * 8,
           &wstage[buf][(rnd * 256 + wv * 64) * 8]);
    }
  };

  stage(0, 0, 0);  // async prefetch of W chunk 0 under the reduction
  // ---- fused reduction: 64 rows x 256 cols, 16 chunks, coalesced float4 ----
#pragma unroll 4
  for (int e = 0; e < 16; ++e) {
    const int u = e * 256 + t;            // float4 unit 0..4095
    const int row = u >> 6, c4 = u & 63;  // cols c4*4..+3
    const float* pp = P + (size_t)(r0 + row) * 256 + c4 * 4;
    float4 s4 = {0.f, 0.f, 0.f, 0.f};
#pragma unroll
    for (int c = 0; c < 16; ++c) {
      float4 v = *(const float4*)(pp + (size_t)c * 65536);
      s4.x += v.x; s4.y += v.y; s4.z += v.z; s4.w += v.w;
    }
    _Float16 h4[4] = {(_Float16)s4.x, (_Float16)s4.y,
                      (_Float16)s4.z, (_Float16)s4.w};
    const int boff = row * 512 + ((c4 * 8) ^ ((row & 7) << 4));
    *(uint2*)((char*)a_lds + boff) = *(const uint2*)h4;
  }
  __syncthreads();

  // ---- main loop (r9 structure; A-frags from a_lds) -----------------------
  f32x4 yacc[16];
#pragma unroll
  for (int i = 0; i < 16; ++i) yacc[i] = {0.f, 0.f, 0.f, 0.f};
  const int arow = wv * 16 + l15;  // local row 0..63
  for (int ci = 0; ci < 16; ++ci) {
    const int nh = ci & 1, ks = ci >> 1;
    if (ci < 15) stage(((ci + 1) & 1) * 128, ((ci + 1) >> 1) * 32, (ci + 1) & 1);
    f16x8 afrag = *(const f16x8*)((char*)a_lds + arow * 512 +
                                  ((ks * 64 + g * 16) ^ ((arow & 7) << 4)));
    const _Float16* cw = wstage[ci & 1];
#pragma unroll
    for (int tt = 0; tt < 8; ++tt) {
      f16x8 bfr = *(const f16x8*)&cw[((tt * 16 + l15) * 32 + g * 8) ^
                                     ((l15 & 7) << 3)];
      yacc[nh * 8 + tt] = MFMA_H(afrag, bfr, yacc[nh * 8 + tt]);
    }
    __syncthreads();
  }
#pragma unroll
  for (int tt = 0; tt < 16; ++tt)
#pragma unroll
    for (int r = 0; r < 4; ++r) {
      const int rowi = r0 + wv * 16 + g * 4 + r;
      const int c = tt * 16 + l15;
      const int hh = c >> 5, d = c & 31;
      const ushort_t val = f2bf(yacc[tt][r]);
      if (which == 0) {
        klowA[(hh << 13) + ((((rowi & 255) << 5) | d) ^ ((rowi & 7) << 3))] = val;
      } else {
        const int kh = (rowi >> 7) & 1, kl = rowi & 127;
        vtb[(((hh * 2 + kh) * 32 + d) << 7) + (kl ^ ((d & 7) << 3))] = val;
      }
    }
}

// ---------------------------------------------------------------------------
// L4: attention. grid (128 tiles of 256 rows, 8 heads), 512 thr.
// Each wave: 2 row-subtiles against one staged KV head slice. (r9-exact +
// uint2/b64 p_buf writes)
__global__ __launch_bounds__(512, 4) void k_attn(
    const ushort_t* __restrict__ Qf, const ushort_t* __restrict__ klowA,
    const ushort_t* __restrict__ vtb, ushort_t* __restrict__ O) {
  __shared__ __align__(16) ushort_t kv[16384];  // klow 8192u | vt 8192u
  __shared__ __align__(16) uint32_t p_buf[8][320];
  __shared__ __align__(16) ushort_t o_sl[8][640];
  const int t = threadIdx.x;
  const int wv = t >> 6, ln = t & 63;
  const int l15 = ln & 15, g = ln >> 4;
  const int h = blockIdx.y;
  const size_t r0 = (size_t)blockIdx.x * 256;

  {  // stage one head's klowA + vtb (32 KB), pre-swizzled -> linear
    const ushort_t* ksrc = klowA + h * 8192;
    const ushort_t* vsrc = vtb + h * 8192;
#pragma unroll
    for (int rnd = 0; rnd < 2; ++rnd) {
      const int ub = rnd * 512 + wv * 64;
      GLDS(ksrc + (ub + ln) * 8, &kv[ub * 8]);
    }
#pragma unroll
    for (int rnd = 0; rnd < 2; ++rnd) {
      const int ub = rnd * 512 + wv * 64;
      GLDS(vsrc + (ub + ln) * 8, &kv[8192 + ub * 8]);
    }
  }
  const int rtb = blockIdx.x * 16 + wv;
  bf16x8 qfA = *(const bf16x8*)&Qf[((size_t)(rtb * 8 + h) * 64 + ln) * 8];
  bf16x8 qfB = *(const bf16x8*)&Qf[((size_t)((rtb + 8) * 8 + h) * 64 + ln) * 8];
  __syncthreads();

#pragma unroll
  for (int st = 0; st < 2; ++st) {
    const bf16x8 qfrag = st ? qfB : qfA;
    // scores: St = mfma(klow, Q)
    f32x4 s[16];
#pragma unroll
    for (int tt = 0; tt < 16; ++tt) {
      bf16x8 kfr = *(const bf16x8*)&kv[((tt * 16 + l15) * 32 + g * 8) ^
                                       ((l15 & 7) << 3)];
      f32x4 z = {0.f, 0.f, 0.f, 0.f};
      s[tt] = MFMA(kfr, qfrag, z);
    }
    // exp2-domain softmax (no max-subtract; log2e*scale folded into Wq)
    float sum = 0.f;
    uint32_t pw[16][2];
#pragma unroll
    for (int tt = 0; tt < 16; ++tt) {
      float e0 = exp2f(s[tt][0]), e1 = exp2f(s[tt][1]);
      float e2 = exp2f(s[tt][2]), e3 = exp2f(s[tt][3]);
      sum += (e0 + e1) + (e2 + e3);
      pw[tt][0] = cvt_pk_bf16(e0, e1);
      pw[tt][1] = cvt_pk_bf16(e2, e3);
    }
    sum += __shfl_xor(sum, 16);
    sum += __shfl_xor(sum, 32);
    const float rinv = 1.0f / sum;
    float rv[4];
#pragma unroll
    for (int r = 0; r < 4; ++r) rv[r] = __shfl(rinv, g * 4 + r);

    // PV via per-wave p_buf repack (b64 writes)
    f32x4 oacc[2];
    oacc[0] = {0.f, 0.f, 0.f, 0.f};
    oacc[1] = {0.f, 0.f, 0.f, 0.f};
    uint32_t* pbw = &p_buf[wv][l15 * 20];
#pragma unroll
    for (int kh = 0; kh < 2; ++kh) {
      const char* cv = (const char*)&kv[8192 + kh * 4096];
#pragma unroll
      for (int ksl = 0; ksl < 4; ++ksl) {
        const int ks = kh * 4 + ksl;
        uint2 w0, w1;
        w0.x = pw[2 * ks][0];     w0.y = pw[2 * ks][1];
        w1.x = pw[2 * ks + 1][0]; w1.y = pw[2 * ks + 1][1];
        *(uint2*)&pbw[2 * g] = w0;
        *(uint2*)&pbw[8 + 2 * g] = w1;
        __builtin_amdgcn_sched_barrier(0);
        bf16x8 pfr = *(const bf16x8*)&p_buf[wv][l15 * 20 + 4 * g];
#pragma unroll
        for (int nt = 0; nt < 2; ++nt) {
          bf16x8 vfr = *(const bf16x8*)(cv + (nt * 16 + l15) * 256 +
                                        ((ksl * 64 + g * 16) ^ ((l15 & 7) << 4)));
          oacc[nt] = MFMA(pfr, vfr, oacc[nt]);
        }
        __builtin_amdgcn_sched_barrier(0);
      }
    }
    // O write via per-wave repack (bf16, coalesced 16B stores)
#pragma unroll
    for (int nt = 0; nt < 2; ++nt)
#pragma unroll
      for (int r = 0; r < 4; ++r)
        o_sl[wv][(g * 4 + r) * 40 + nt * 16 + l15] = f2bf(oacc[nt][r] * rv[r]);
    __builtin_amdgcn_sched_barrier(0);
    {
      const int qr = ln >> 2, d0 = (ln & 3) * 8;
      bf16x8 ov = *(const bf16x8*)&o_sl[wv][qr * 40 + d0];
      *(bf16x8*)&O[(r0 + st * 128 + wv * 16 + qr) * 256 + h * 32 + d0] = ov;
    }
    __builtin_amdgcn_sched_barrier(0);
  }
}

// ---------------------------------------------------------------------------
// L5: out = O @ wot^T (f32). grid 512, 256 thr. (unchanged)
__global__ __launch_bounds__(256, 4) void k_ogemm(
    const ushort_t* __restrict__ O, const ushort_t* __restrict__ wot,
    float* __restrict__ out) {
  __shared__ __align__(16) ushort_t wstage[2][4096];
  const int t = threadIdx.x;
  const int wv = t >> 6, ln = t & 63;
  const int l15 = ln & 15, g = ln >> 4;
  const size_t r0 = (size_t)blockIdx.x * 64;

  auto stage = [&](int row0, int colu, int buf) {
#pragma unroll
    for (int rnd = 0; rnd < 2; ++rnd) {
      const int u = rnd * 256 + wv * 64 + ln;
      const int row = STAGE_ROW(u);
      const int gg = STAGE_G(u);
      GLDS(wot + (size_t)(row0 + row) * 256 + colu + gg * 8,
           &wstage[buf][(rnd * 256 + wv * 64) * 8]);
    }
  };

  f32x4 yacc[16];
#pragma unroll
  for (int i = 0; i < 16; ++i) yacc[i] = {0.f, 0.f, 0.f, 0.f};
  stage(0, 0, 0);
  const ushort_t* arow = O + (r0 + wv * 16 + l15) * 256;
  __syncthreads();
  for (int ci = 0; ci < 16; ++ci) {
    const int nh = ci & 1, ks = ci >> 1;
    if (ci < 15) stage(((ci + 1) & 1) * 128, ((ci + 1) >> 1) * 32, (ci + 1) & 1);
    bf16x8 afrag = *(const bf16x8*)(arow + ks * 32 + g * 8);
    const ushort_t* cw = wstage[ci & 1];
#pragma unroll
    for (int tt = 0; tt < 8; ++tt) {
      bf16x8 bfr = *(const bf16x8*)&cw[((tt * 16 + l15) * 32 + g * 8) ^
                                       ((l15 & 7) << 3)];
      yacc[nh * 8 + tt] = MFMA(afrag, bfr, yacc[nh * 8 + tt]);
    }
    __syncthreads();
  }
#pragma unroll
  for (int tt = 0; tt < 16; ++tt)
#pragma unroll
    for (int r = 0; r < 4; ++r)
      out[(r0 + wv * 16 + g * 4 + r) * 256 + tt * 16 + l15] = yacc[tt][r];
}

extern "C" void kernel_launch(void* const* d_in, const int* in_sizes, int n_in,
                              void* d_out, int out_size, void* d_ws, size_t ws_size,
                              hipStream_t stream) {
  const float* x1 = (const float*)d_in[0];
  const float* x2 = (const float*)d_in[1];
  const float* Wq = (const float*)d_in[2];
  const float* Wk = (const float*)d_in[3];
  const float* Wv = (const float*)d_in[4];
  const float* Wo = (const float*)d_in[5];
  const float* E  = (const float*)d_in[6];
  const float* F  = (const float*)d_in[7];
  float* out = (float*)d_out;
  float* ws = (float*)d_ws;
  // ws layout (float offsets):
  //  (unused @0..65536) | wqt @65536 | wot @98304 | wkt @131072 | wvt @163840
  //  klowA @196608 | vtb @229376 | part f32 @262144 (2,097,152)
  //  Qf bf16 @2359296 (4,194,304) | xt fp16 @6553600 (3,145,728)
  //  O bf16 @6553600 overlays xt (xt dead after L2)
  ushort_t* wqt = (ushort_t*)(ws + 65536);
  ushort_t* wot = (ushort_t*)(ws + 98304);
  _Float16* wkt = (_Float16*)(ws + 131072);
  _Float16* wvt = (_Float16*)(ws + 163840);
  ushort_t* klowA = (ushort_t*)(ws + 196608);
  ushort_t* vtb = (ushort_t*)(ws + 229376);
  float* part = ws + 262144;
  ushort_t* Qf = (ushort_t*)(ws + 2359296);
  _Float16* xt = (_Float16*)(ws + 6553600);
  ushort_t* O = (ushort_t*)(ws + 6553600);

  k_prep_all<<<dim3(128, 4, 4), 256, 0, stream>>>(x2, E, F, Wq, Wk, Wv, Wo, xt,
                                                  wqt, wot, wkt, wvt);
  k_mega1<<<640, 256, 0, stream>>>(x1, xt, wqt, Qf, part);
  k_lowproj2<<<dim3(4, 2), 256, 0, stream>>>(part, wkt, wvt, klowA, vtb);
  k_attn<<<dim3(128, 8), 512, 0, stream>>>(Qf, klowA, vtb, O);
  k_ogemm<<<512, 256, 0, stream>>>(O, wot, out);
}

// Round 14
// 83.611 us; speedup vs baseline: 1.4574x; 1.4574x over previous
//
#include <hip/hip_runtime.h>
#include <math.h>
#include <stdint.h>

// B=4, NQ=8192, NKV=8192, D=256, H=8, HD=32, KP=256. ROWS = 32768.
// Round-9 configuration EXACT (best measured: 83.9 us), sole carry-over:
// uint2 (ds_write_b64) p_buf writes in attn.
// L1 k_prep_all: x2,E,F -> xt fp16 [3][256][8192] (transposed); W transposes
// L2 k_mega1:    qgemm (512 blks): Qf = x1@Wq^T (B-frag layout)
//                + etx2 (128 blks): part = E^T x2 / F^T x2 (fp16 MFMA splitK16)
// L3 k_reduce:   sum 16 partials -> ghh fp16 (512 blks)
// L4 k_lowproj2: klow=G@Wk, vlow=Hh@Wv (fp16 MFMA) -> klowA/vtb direct
// L5 k_attn:     per (256-row tile, head): St=mfma(klow,Q), exp2 softmax,
//                PV -> O bf16 (2 row-subtiles per staged KV)
// L6 k_ogemm:    out = O @ Wo^T (f32)

typedef unsigned short ushort_t;
typedef __attribute__((ext_vector_type(8))) short bf16x8;
typedef __attribute__((ext_vector_type(8))) _Float16 f16x8;
typedef __attribute__((ext_vector_type(4))) float f32x4;

__device__ __forceinline__ f32x4 MFMA(bf16x8 a, bf16x8 b, f32x4 c) {
  return __builtin_amdgcn_mfma_f32_16x16x32_bf16(a, b, c, 0, 0, 0);
}
__device__ __forceinline__ f32x4 MFMA_H(f16x8 a, f16x8 b, f32x4 c) {
  return __builtin_amdgcn_mfma_f32_16x16x32_f16(a, b, c, 0, 0, 0);
}
__device__ __forceinline__ ushort_t f2bf(float x) {
  uint32_t u = __float_as_uint(x);
  u += 0x7fffu + ((u >> 16) & 1u);
  return (ushort_t)(u >> 16);
}
// packed f32 pair -> bf16x2 in one VALU op (lo = a, hi = b)
__device__ __forceinline__ uint32_t cvt_pk_bf16(float a, float b) {
  uint32_t r;
  asm("v_cvt_pk_bf16_f32 %0, %1, %2" : "=v"(r) : "v"(a), "v"(b));
  return r;
}
#define GLDS(gsrc, ldst)                                                    \
  __builtin_amdgcn_global_load_lds(                                         \
      (const __attribute__((address_space(1))) uint32_t*)(const void*)(gsrc), \
      (__attribute__((address_space(3))) uint32_t*)(void*)(ldst), 16, 0, 0)

// 3-bit XOR chunk staging helpers (proven rounds 3-9)
#define STAGE_ROW(u) \
  (((((u) >> 2) ^ ((u) >> 4)) & 1) | (((u) >> 2) & 6) | (((u) >> 5) << 3))
#define STAGE_G(u) \
  ((((u) ^ ((u) >> 2) ^ ((u) >> 4)) & 1) | (((((u) >> 1) ^ ((u) >> 3)) & 1) << 1))

// ---------------------------------------------------------------------------
// L1: transposes. grid (128,4,4), 256 thr.
__global__ __launch_bounds__(256) void k_prep_all(
    const float* __restrict__ x2, const float* __restrict__ E,
    const float* __restrict__ F, const float* __restrict__ Wq,
    const float* __restrict__ Wk, const float* __restrict__ Wv,
    const float* __restrict__ Wo, _Float16* __restrict__ xt,
    ushort_t* __restrict__ wqt, ushort_t* __restrict__ wot,
    _Float16* __restrict__ wkt, _Float16* __restrict__ wvt) {
  __shared__ float tile[64][65];
  const int t = threadIdx.x;
  const int z = blockIdx.z;
  if (z < 3) {
    const int n0 = blockIdx.x * 64;
    const int c0 = blockIdx.y * 64;
    const float* __restrict__ src = (z == 0) ? x2 : (z == 1) ? E : F;
    _Float16* __restrict__ dst = xt + (size_t)z * 2097152;
    const int rr = t >> 4, cc = (t & 15) * 4;
#pragma unroll
    for (int i = 0; i < 4; ++i) {
      float4 v = *(const float4*)&src[(size_t)(n0 + rr + 16 * i) * 256 + c0 + cc];
      tile[cc + 0][rr + 16 * i] = v.x;
      tile[cc + 1][rr + 16 * i] = v.y;
      tile[cc + 2][rr + 16 * i] = v.z;
      tile[cc + 3][rr + 16 * i] = v.w;
    }
    __syncthreads();
#pragma unroll
    for (int rnd = 0; rnd < 2; ++rnd) {
      const int u = rnd * 256 + t;
      const int c = u >> 3, r0 = (u & 7) * 8;
      f16x8 h;
#pragma unroll
      for (int j = 0; j < 8; ++j) h[j] = (_Float16)tile[c][r0 + j];
      *(f16x8*)&dst[(size_t)(c0 + c) * 8192 + n0 + r0] = h;
    }
  } else {
    if (blockIdx.x >= 16) return;
    const int m = blockIdx.y;
    const float* __restrict__ src = (m == 0) ? Wq : (m == 1) ? Wo
                                  : (m == 2) ? Wk : Wv;
    const int tr = (blockIdx.x >> 2) * 64;
    const int tc = (blockIdx.x & 3) * 64;
    const int rr = t >> 4, cc = (t & 15) * 4;
#pragma unroll
    for (int i = 0; i < 4; ++i) {
      float4 v = *(const float4*)&src[(size_t)(tr + rr + 16 * i) * 256 + tc + cc];
      tile[cc + 0][rr + 16 * i] = v.x;
      tile[cc + 1][rr + 16 * i] = v.y;
      tile[cc + 2][rr + 16 * i] = v.z;
      tile[cc + 3][rr + 16 * i] = v.w;
    }
    __syncthreads();
#pragma unroll
    for (int rnd = 0; rnd < 2; ++rnd) {
      const int u = rnd * 256 + t;
      const int nl = u >> 3, kl = (u & 7) * 8;
      if (m < 2) {
        const float sc = (m == 0) ? 0.25503488f : 1.0f;  // scale*log2e
        bf16x8 hv;
#pragma unroll
        for (int j = 0; j < 8; ++j) hv[j] = (short)f2bf(tile[nl][kl + j] * sc);
        ushort_t* dst = (m == 0) ? wqt : wot;
        *(bf16x8*)&dst[(size_t)(tc + nl) * 256 + tr + kl] = hv;
      } else {
        f16x8 hv;
#pragma unroll
        for (int j = 0; j < 8; ++j) hv[j] = (_Float16)tile[nl][kl + j];
        _Float16* dst = (m == 2) ? wkt : wvt;
        *(f16x8*)&dst[(size_t)(tc + nl) * 256 + tr + kl] = hv;
      }
    }
  }
}

// ---------------------------------------------------------------------------
// L2: merged qgemm (bid<512) + etx2 (bid>=512, splitK16). grid 640, 256 thr.
__global__ __launch_bounds__(256, 3) void k_mega1(
    const float* __restrict__ x1, const _Float16* __restrict__ xt,
    const ushort_t* __restrict__ wqt, ushort_t* __restrict__ Qf,
    float* __restrict__ part) {
  __shared__ __align__(16) char smem[32768];
  const int t = threadIdx.x;
  const int wv = t >> 6, ln = t & 63;
  const int l15 = ln & 15, g = ln >> 4;

  if (blockIdx.x < 512) {
    // ---------------- qgemm: Qf = x1 @ wqt^T (B-frag layout) ----------------
    ushort_t* wstage = (ushort_t*)smem;
    const size_t r0 = (size_t)blockIdx.x * 64;
    auto stage = [&](int row0, int colu, int buf) {
#pragma unroll
      for (int rnd = 0; rnd < 2; ++rnd) {
        const int u = rnd * 256 + wv * 64 + ln;
        const int row = STAGE_ROW(u);
        const int gg = STAGE_G(u);
        GLDS(wqt + (size_t)(row0 + row) * 256 + colu + gg * 8,
             &wstage[(buf * 512 + rnd * 256 + wv * 64) * 8]);
      }
    };
    f32x4 qacc[16];
#pragma unroll
    for (int i = 0; i < 16; ++i) qacc[i] = {0.f, 0.f, 0.f, 0.f};
    stage(0, 0, 0);
    const float* xrow = x1 + (r0 + wv * 16 + l15) * 256;
    float4 xa = *(const float4*)(xrow + g * 8);
    float4 xb = *(const float4*)(xrow + g * 8 + 4);
    __syncthreads();
    for (int ci = 0; ci < 16; ++ci) {
      const int nh = ci & 1;
      if (ci < 15) stage(((ci + 1) & 1) * 128, ((ci + 1) >> 1) * 32, (ci + 1) & 1);
      union { uint32_t u[4]; bf16x8 v; } af;
      af.u[0] = cvt_pk_bf16(xa.x, xa.y);
      af.u[1] = cvt_pk_bf16(xa.z, xa.w);
      af.u[2] = cvt_pk_bf16(xb.x, xb.y);
      af.u[3] = cvt_pk_bf16(xb.z, xb.w);
      const bf16x8 afrag = af.v;
      const ushort_t* cw = &wstage[(ci & 1) * 4096];
#pragma unroll
      for (int tt = 0; tt < 8; ++tt) {
        bf16x8 bfr = *(const bf16x8*)&cw[((tt * 16 + l15) * 32 + g * 8) ^
                                         ((l15 & 7) << 3)];
        qacc[nh * 8 + tt] = MFMA(afrag, bfr, qacc[nh * 8 + tt]);
      }
      if (nh == 1 && ci < 15) {
        int ks = (ci >> 1) + 1;
        xa = *(const float4*)(xrow + ks * 32 + g * 8);
        xb = *(const float4*)(xrow + ks * 32 + g * 8 + 4);
      }
      __syncthreads();
    }
    char* myq = smem + wv * 8192;
#pragma unroll
    for (int tt = 0; tt < 16; ++tt)
#pragma unroll
      for (int r = 0; r < 4; ++r) {
        const int gr = g * 4 + r;
        *(ushort_t*)(myq + gr * 512 + (((tt * 16 + l15) * 2) ^ ((gr & 7) << 4))) =
            f2bf(qacc[tt][r]);
      }
    __builtin_amdgcn_sched_barrier(0);
    const int rt = blockIdx.x * 4 + wv;
#pragma unroll
    for (int hh = 0; hh < 8; ++hh) {
      bf16x8 qf = *(const bf16x8*)(myq + l15 * 512 +
                                   ((hh * 64 + g * 16) ^ ((l15 & 7) << 4)));
      *(bf16x8*)&Qf[((size_t)(rt * 8 + hh) * 64 + ln) * 8] = qf;
    }
  } else {
    // ---------------- etx2: part = E^T x2 / F^T x2 (splitK 16) --------------
    const int bid = blockIdx.x - 512;  // 0..127
    const int which = bid & 1;
    const int chunk = (bid >> 1) & 15;
    const int quad = bid >> 5;  // 0..3
    const int kp0 = (quad >> 1) * 128;
    const int d0 = (quad & 1) * 128;
    const int n0 = chunk * 512;
    const _Float16* __restrict__ A = xt + (size_t)(1 + which) * 2097152;
    const _Float16* __restrict__ B = xt;
    const int wr = wv >> 1, wc = wv & 1;
    f32x4 acc[4][4];
#pragma unroll
    for (int i = 0; i < 4; ++i)
#pragma unroll
      for (int j = 0; j < 4; ++j) acc[i][j] = {0.f, 0.f, 0.f, 0.f};

    for (int ks = 0; ks < 8; ++ks) {
#pragma unroll
      for (int r8 = 0; r8 < 8; ++r8) {
        const int u = r8 * 256 + t;      // 0..2047 16B units
        const int mm = u >> 10;          // 0:A 1:B
        const int uu = u & 1023;
        const int row = uu >> 3;
        const int nsw = ((uu ^ row) & 7) << 3;  // source-swizzled n-elems
        const _Float16* gs =
            (mm ? B + (size_t)(d0 + row) * 8192
                : A + (size_t)(kp0 + row) * 8192) +
            n0 + ks * 64 + nsw;
        GLDS(gs, smem + (u & ~63) * 16);
      }
      __syncthreads();
      const char* la = smem;
      const char* lb = smem + 16384;
#pragma unroll
      for (int kk = 0; kk < 2; ++kk) {
        f16x8 af[4], bf[4];
#pragma unroll
        for (int i = 0; i < 4; ++i) {
          const int ra = wr * 64 + i * 16 + l15;
          af[i] = *(const f16x8*)(la + ra * 128 +
                                  ((kk * 64 + g * 16) ^ ((ra & 7) << 4)));
        }
#pragma unroll
        for (int j = 0; j < 4; ++j) {
          const int rb = wc * 64 + j * 16 + l15;
          bf[j] = *(const f16x8*)(lb + rb * 128 +
                                  ((kk * 64 + g * 16) ^ ((rb & 7) << 4)));
        }
#pragma unroll
        for (int i = 0; i < 4; ++i)
#pragma unroll
          for (int j = 0; j < 4; ++j)
            acc[i][j] = MFMA_H(af[i], bf[j], acc[i][j]);
      }
      __syncthreads();
    }
    float* __restrict__ p = part + ((size_t)which * 16 + chunk) * 65536;
#pragma unroll
    for (int i = 0; i < 4; ++i)
#pragma unroll
      for (int j = 0; j < 4; ++j)
#pragma unroll
        for (int r = 0; r < 4; ++r)
          p[(size_t)(kp0 + wr * 64 + i * 16 + g * 4 + r) * 256 + d0 + wc * 64 +
            j * 16 + l15] = acc[i][j][r];
  }
}

// ---------------------------------------------------------------------------
// L3: reduce 16 partials -> ghh fp16 [2][65536]. grid 512.
__global__ __launch_bounds__(256) void k_reduce_part(
    const float* __restrict__ part, _Float16* __restrict__ ghh) {
  const int oid = blockIdx.x * 256 + threadIdx.x;
  const int which = oid >> 16;
  const int base = oid & 65535;
  const float* __restrict__ p = part + (size_t)which * 16 * 65536 + base;
  float s = 0.f;
#pragma unroll
  for (int c = 0; c < 16; ++c) s += p[c * 65536];
  ghh[oid] = (_Float16)s;
}

// ---------------------------------------------------------------------------
// L4: klow/vlow proj + direct klowA/vtb epilogue. grid (4,2).
__global__ __launch_bounds__(256, 4) void k_lowproj2(
    const _Float16* __restrict__ ghh, const _Float16* __restrict__ wkt,
    const _Float16* __restrict__ wvt, ushort_t* __restrict__ klowA,
    ushort_t* __restrict__ vtb) {
  __shared__ __align__(16) _Float16 wstage[2][4096];
  const int t = threadIdx.x;
  const int wv = t >> 6, ln = t & 63;
  const int l15 = ln & 15, g = ln >> 4;
  const int which = blockIdx.y;
  const int r0 = blockIdx.x * 64;
  const _Float16* __restrict__ A = ghh + (size_t)which * 65536;
  const _Float16* __restrict__ W = which ? wvt : wkt;

  auto stage = [&](int row0, int colu, int buf) {
#pragma unroll
    for (int rnd = 0; rnd < 2; ++rnd) {
      const int u = rnd * 256 + wv * 64 + ln;
      const int row = STAGE_ROW(u);
      const int gg = STAGE_G(u);
      GLDS(W + (size_t)(row0 + row) * 256 + colu + gg * 8,
           &wstage[buf][(rnd * 256 + wv * 64) * 8]);
    }
  };

  f32x4 yacc[16];
#pragma unroll
  for (int i = 0; i < 16; ++i) yacc[i] = {0.f, 0.f, 0.f, 0.f};
  stage(0, 0, 0);
  const _Float16* arow = A + (size_t)(r0 + wv * 16 + l15) * 256;
  __syncthreads();
  for (int ci = 0; ci < 16; ++ci) {
    const int nh = ci & 1, ks = ci >> 1;
    if (ci < 15) stage(((ci + 1) & 1) * 128, ((ci + 1) >> 1) * 32, (ci + 1) & 1);
    f16x8 afrag = *(const f16x8*)(arow + ks * 32 + g * 8);
    const _Float16* cw = wstage[ci & 1];
#pragma unroll
    for (int tt = 0; tt < 8; ++tt) {
      f16x8 bfr = *(const f16x8*)&cw[((tt * 16 + l15) * 32 + g * 8) ^
                                     ((l15 & 7) << 3)];
      yacc[nh * 8 + tt] = MFMA_H(afrag, bfr, yacc[nh * 8 + tt]);
    }
    __syncthreads();
  }
#pragma unroll
  for (int tt = 0; tt < 16; ++tt)
#pragma unroll
    for (int r = 0; r < 4; ++r) {
      const int rowi = r0 + wv * 16 + g * 4 + r;
      const int c = tt * 16 + l15;
      const int hh = c >> 5, d = c & 31;
      const ushort_t val = f2bf(yacc[tt][r]);
      if (which == 0) {
        klowA[(hh << 13) + ((((rowi & 255) << 5) | d) ^ ((rowi & 7) << 3))] = val;
      } else {
        const int kh = (rowi >> 7) & 1, kl = rowi & 127;
        vtb[(((hh * 2 + kh) * 32 + d) << 7) + (kl ^ ((d & 7) << 3))] = val;
      }
    }
}

// ---------------------------------------------------------------------------
// L5: attention. grid (128 tiles of 256 rows, 8 heads), 512 thr.
// Each wave: 2 row-subtiles against one staged KV head slice.
__global__ __launch_bounds__(512, 4) void k_attn(
    const ushort_t* __restrict__ Qf, const ushort_t* __restrict__ klowA,
    const ushort_t* __restrict__ vtb, ushort_t* __restrict__ O) {
  __shared__ __align__(16) ushort_t kv[16384];  // klow 8192u | vt 8192u
  __shared__ __align__(16) uint32_t p_buf[8][320];
  __shared__ __align__(16) ushort_t o_sl[8][640];
  const int t = threadIdx.x;
  const int wv = t >> 6, ln = t & 63;
  const int l15 = ln & 15, g = ln >> 4;
  const int h = blockIdx.y;
  const size_t r0 = (size_t)blockIdx.x * 256;

  {  // stage one head's klowA + vtb (32 KB), pre-swizzled -> linear
    const ushort_t* ksrc = klowA + h * 8192;
    const ushort_t* vsrc = vtb + h * 8192;
#pragma unroll
    for (int rnd = 0; rnd < 2; ++rnd) {
      const int ub = rnd * 512 + wv * 64;
      GLDS(ksrc + (ub + ln) * 8, &kv[ub * 8]);
    }
#pragma unroll
    for (int rnd = 0; rnd < 2; ++rnd) {
      const int ub = rnd * 512 + wv * 64;
      GLDS(vsrc + (ub + ln) * 8, &kv[8192 + ub * 8]);
    }
  }
  const int rtb = blockIdx.x * 16 + wv;
  bf16x8 qfA = *(const bf16x8*)&Qf[((size_t)(rtb * 8 + h) * 64 + ln) * 8];
  bf16x8 qfB = *(const bf16x8*)&Qf[((size_t)((rtb + 8) * 8 + h) * 64 + ln) * 8];
  __syncthreads();

#pragma unroll
  for (int st = 0; st < 2; ++st) {
    const bf16x8 qfrag = st ? qfB : qfA;
    // scores: St = mfma(klow, Q)
    f32x4 s[16];
#pragma unroll
    for (int tt = 0; tt < 16; ++tt) {
      bf16x8 kfr = *(const bf16x8*)&kv[((tt * 16 + l15) * 32 + g * 8) ^
                                       ((l15 & 7) << 3)];
      f32x4 z = {0.f, 0.f, 0.f, 0.f};
      s[tt] = MFMA(kfr, qfrag, z);
    }
    // exp2-domain softmax (no max-subtract; log2e*scale folded into Wq)
    float sum = 0.f;
    uint32_t pw[16][2];
#pragma unroll
    for (int tt = 0; tt < 16; ++tt) {
      float e0 = exp2f(s[tt][0]), e1 = exp2f(s[tt][1]);
      float e2 = exp2f(s[tt][2]), e3 = exp2f(s[tt][3]);
      sum += (e0 + e1) + (e2 + e3);
      pw[tt][0] = cvt_pk_bf16(e0, e1);
      pw[tt][1] = cvt_pk_bf16(e2, e3);
    }
    sum += __shfl_xor(sum, 16);
    sum += __shfl_xor(sum, 32);
    const float rinv = 1.0f / sum;
    float rv[4];
#pragma unroll
    for (int r = 0; r < 4; ++r) rv[r] = __shfl(rinv, g * 4 + r);

    // PV via per-wave p_buf repack (b64 writes)
    f32x4 oacc[2];
    oacc[0] = {0.f, 0.f, 0.f, 0.f};
    oacc[1] = {0.f, 0.f, 0.f, 0.f};
    uint32_t* pbw = &p_buf[wv][l15 * 20];
#pragma unroll
    for (int kh = 0; kh < 2; ++kh) {
      const char* cv = (const char*)&kv[8192 + kh * 4096];
#pragma unroll
      for (int ksl = 0; ksl < 4; ++ksl) {
        const int ks = kh * 4 + ksl;
        uint2 w0, w1;
        w0.x = pw[2 * ks][0];     w0.y = pw[2 * ks][1];
        w1.x = pw[2 * ks + 1][0]; w1.y = pw[2 * ks + 1][1];
        *(uint2*)&pbw[2 * g] = w0;
        *(uint2*)&pbw[8 + 2 * g] = w1;
        __builtin_amdgcn_sched_barrier(0);
        bf16x8 pfr = *(const bf16x8*)&p_buf[wv][l15 * 20 + 4 * g];
#pragma unroll
        for (int nt = 0; nt < 2; ++nt) {
          bf16x8 vfr = *(const bf16x8*)(cv + (nt * 16 + l15) * 256 +
                                        ((ksl * 64 + g * 16) ^ ((l15 & 7) << 4)));
          oacc[nt] = MFMA(pfr, vfr, oacc[nt]);
        }
        __builtin_amdgcn_sched_barrier(0);
      }
    }
    // O write via per-wave repack (bf16, coalesced 16B stores)
#pragma unroll
    for (int nt = 0; nt < 2; ++nt)
#pragma unroll
      for (int r = 0; r < 4; ++r)
        o_sl[wv][(g * 4 + r) * 40 + nt * 16 + l15] = f2bf(oacc[nt][r] * rv[r]);
    __builtin_amdgcn_sched_barrier(0);
    {
      const int qr = ln >> 2, d0 = (ln & 3) * 8;
      bf16x8 ov = *(const bf16x8*)&o_sl[wv][qr * 40 + d0];
      *(bf16x8*)&O[(r0 + st * 128 + wv * 16 + qr) * 256 + h * 32 + d0] = ov;
    }
    __builtin_amdgcn_sched_barrier(0);
  }
}

// ---------------------------------------------------------------------------
// L6: out = O @ wot^T (f32). grid 512, 256 thr.
__global__ __launch_bounds__(256, 4) void k_ogemm(
    const ushort_t* __restrict__ O, const ushort_t* __restrict__ wot,
    float* __restrict__ out) {
  __shared__ __align__(16) ushort_t wstage[2][4096];
  const int t = threadIdx.x;
  const int wv = t >> 6, ln = t & 63;
  const int l15 = ln & 15, g = ln >> 4;
  const size_t r0 = (size_t)blockIdx.x * 64;

  auto stage = [&](int row0, int colu, int buf) {
#pragma unroll
    for (int rnd = 0; rnd < 2; ++rnd) {
      const int u = rnd * 256 + wv * 64 + ln;
      const int row = STAGE_ROW(u);
      const int gg = STAGE_G(u);
      GLDS(wot + (size_t)(row0 + row) * 256 + colu + gg * 8,
           &wstage[buf][(rnd * 256 + wv * 64) * 8]);
    }
  };

  f32x4 yacc[16];
#pragma unroll
  for (int i = 0; i < 16; ++i) yacc[i] = {0.f, 0.f, 0.f, 0.f};
  stage(0, 0, 0);
  const ushort_t* arow = O + (r0 + wv * 16 + l15) * 256;
  __syncthreads();
  for (int ci = 0; ci < 16; ++ci) {
    const int nh = ci & 1, ks = ci >> 1;
    if (ci < 15) stage(((ci + 1) & 1) * 128, ((ci + 1) >> 1) * 32, (ci + 1) & 1);
    bf16x8 afrag = *(const bf16x8*)(arow + ks * 32 + g * 8);
    const ushort_t* cw = wstage[ci & 1];
#pragma unroll
    for (int tt = 0; tt < 8; ++tt) {
      bf16x8 bfr = *(const bf16x8*)&cw[((tt * 16 + l15) * 32 + g * 8) ^
                                       ((l15 & 7) << 3)];
      yacc[nh * 8 + tt] = MFMA(afrag, bfr, yacc[nh * 8 + tt]);
    }
    __syncthreads();
  }
#pragma unroll
  for (int tt = 0; tt < 16; ++tt)
#pragma unroll
    for (int r = 0; r < 4; ++r)
      out[(r0 + wv * 16 + g * 4 + r) * 256 + tt * 16 + l15] = yacc[tt][r];
}

extern "C" void kernel_launch(void* const* d_in, const int* in_sizes, int n_in,
                              void* d_out, int out_size, void* d_ws, size_t ws_size,
                              hipStream_t stream) {
  const float* x1 = (const float*)d_in[0];
  const float* x2 = (const float*)d_in[1];
  const float* Wq = (const float*)d_in[2];
  const float* Wk = (const float*)d_in[3];
  const float* Wv = (const float*)d_in[4];
  const float* Wo = (const float*)d_in[5];
  const float* E  = (const float*)d_in[6];
  const float* F  = (const float*)d_in[7];
  float* out = (float*)d_out;
  float* ws = (float*)d_ws;
  // ws layout (float offsets):
  //  ghh fp16 @0 (65536) | wqt @65536 | wot @98304 | wkt @131072 | wvt @163840
  //  klowA @196608 | vtb @229376 | part f32 @262144 (2,097,152)
  //  Qf bf16 @2359296 (4,194,304) | xt fp16 @6553600 (3,145,728)
  //  O bf16 @6553600 overlays xt (xt dead after L2)
  _Float16* ghh = (_Float16*)ws;
  ushort_t* wqt = (ushort_t*)(ws + 65536);
  ushort_t* wot = (ushort_t*)(ws + 98304);
  _Float16* wkt = (_Float16*)(ws + 131072);
  _Float16* wvt = (_Float16*)(ws + 163840);
  ushort_t* klowA = (ushort_t*)(ws + 196608);
  ushort_t* vtb = (ushort_t*)(ws + 229376);
  float* part = ws + 262144;
  ushort_t* Qf = (ushort_t*)(ws + 2359296);
  _Float16* xt = (_Float16*)(ws + 6553600);
  ushort_t* O = (ushort_t*)(ws + 6553600);

  k_prep_all<<<dim3(128, 4, 4), 256, 0, stream>>>(x2, E, F, Wq, Wk, Wv, Wo, xt,
                                                  wqt, wot, wkt, wvt);
  k_mega1<<<640, 256, 0, stream>>>(x1, xt, wqt, Qf, part);
  k_reduce_part<<<512, 256, 0, stream>>>(part, ghh);
  k_lowproj2<<<dim3(4, 2), 256, 0, stream>>>(ghh, wkt, wvt, klowA, vtb);
  k_attn<<<dim3(128, 8), 512, 0, stream>>>(Qf, klowA, vtb, O);
  k_ogemm<<<512, 256, 0, stream>>>(O, wot, out);
}

// Round 15
// 83.466 us; speedup vs baseline: 1.4599x; 1.0017x over previous
//
#include <hip/hip_runtime.h>
#include <math.h>
#include <stdint.h>

// B=4, NQ=8192, NKV=8192, D=256, H=8, HD=32, KP=256. ROWS = 32768.
// Round-14 (83.6 us) + fp16 split-K partials (halves part traffic).
// L1 k_prep_all: x2,E,F -> xt fp16 [3][256][8192] (transposed); W transposes
// L2 k_mega1:    qgemm (512 blks): Qf = x1@Wq^T (B-frag layout)
//                + etx2 (128 blks): part16 = E^T x2 / F^T x2 (fp16 MFMA sK16)
// L3 k_reduce:   sum 16 fp16 partials (f32 accum) -> ghh fp16 (512 blks)
// L4 k_lowproj2: klow=G@Wk, vlow=Hh@Wv (fp16 MFMA) -> klowA/vtb direct
// L5 k_attn:     per (256-row tile, head): St=mfma(klow,Q), exp2 softmax,
//                PV -> O bf16 (2 row-subtiles per staged KV)
// L6 k_ogemm:    out = O @ Wo^T (f32)

typedef unsigned short ushort_t;
typedef __attribute__((ext_vector_type(8))) short bf16x8;
typedef __attribute__((ext_vector_type(8))) _Float16 f16x8;
typedef __attribute__((ext_vector_type(4))) float f32x4;

__device__ __forceinline__ f32x4 MFMA(bf16x8 a, bf16x8 b, f32x4 c) {
  return __builtin_amdgcn_mfma_f32_16x16x32_bf16(a, b, c, 0, 0, 0);
}
__device__ __forceinline__ f32x4 MFMA_H(f16x8 a, f16x8 b, f32x4 c) {
  return __builtin_amdgcn_mfma_f32_16x16x32_f16(a, b, c, 0, 0, 0);
}
__device__ __forceinline__ ushort_t f2bf(float x) {
  uint32_t u = __float_as_uint(x);
  u += 0x7fffu + ((u >> 16) & 1u);
  return (ushort_t)(u >> 16);
}
// packed f32 pair -> bf16x2 in one VALU op (lo = a, hi = b)
__device__ __forceinline__ uint32_t cvt_pk_bf16(float a, float b) {
  uint32_t r;
  asm("v_cvt_pk_bf16_f32 %0, %1, %2" : "=v"(r) : "v"(a), "v"(b));
  return r;
}
#define GLDS(gsrc, ldst)                                                    \
  __builtin_amdgcn_global_load_lds(                                         \
      (const __attribute__((address_space(1))) uint32_t*)(const void*)(gsrc), \
      (__attribute__((address_space(3))) uint32_t*)(void*)(ldst), 16, 0, 0)

// 3-bit XOR chunk staging helpers (proven rounds 3-14)
#define STAGE_ROW(u) \
  (((((u) >> 2) ^ ((u) >> 4)) & 1) | (((u) >> 2) & 6) | (((u) >> 5) << 3))
#define STAGE_G(u) \
  ((((u) ^ ((u) >> 2) ^ ((u) >> 4)) & 1) | (((((u) >> 1) ^ ((u) >> 3)) & 1) << 1))

// ---------------------------------------------------------------------------
// L1: transposes. grid (128,4,4), 256 thr. (unchanged, proven)
__global__ __launch_bounds__(256) void k_prep_all(
    const float* __restrict__ x2, const float* __restrict__ E,
    const float* __restrict__ F, const float* __restrict__ Wq,
    const float* __restrict__ Wk, const float* __restrict__ Wv,
    const float* __restrict__ Wo, _Float16* __restrict__ xt,
    ushort_t* __restrict__ wqt, ushort_t* __restrict__ wot,
    _Float16* __restrict__ wkt, _Float16* __restrict__ wvt) {
  __shared__ float tile[64][65];
  const int t = threadIdx.x;
  const int z = blockIdx.z;
  if (z < 3) {
    const int n0 = blockIdx.x * 64;
    const int c0 = blockIdx.y * 64;
    const float* __restrict__ src = (z == 0) ? x2 : (z == 1) ? E : F;
    _Float16* __restrict__ dst = xt + (size_t)z * 2097152;
    const int rr = t >> 4, cc = (t & 15) * 4;
#pragma unroll
    for (int i = 0; i < 4; ++i) {
      float4 v = *(const float4*)&src[(size_t)(n0 + rr + 16 * i) * 256 + c0 + cc];
      tile[cc + 0][rr + 16 * i] = v.x;
      tile[cc + 1][rr + 16 * i] = v.y;
      tile[cc + 2][rr + 16 * i] = v.z;
      tile[cc + 3][rr + 16 * i] = v.w;
    }
    __syncthreads();
#pragma unroll
    for (int rnd = 0; rnd < 2; ++rnd) {
      const int u = rnd * 256 + t;
      const int c = u >> 3, r0 = (u & 7) * 8;
      f16x8 h;
#pragma unroll
      for (int j = 0; j < 8; ++j) h[j] = (_Float16)tile[c][r0 + j];
      *(f16x8*)&dst[(size_t)(c0 + c) * 8192 + n0 + r0] = h;
    }
  } else {
    if (blockIdx.x >= 16) return;
    const int m = blockIdx.y;
    const float* __restrict__ src = (m == 0) ? Wq : (m == 1) ? Wo
                                  : (m == 2) ? Wk : Wv;
    const int tr = (blockIdx.x >> 2) * 64;
    const int tc = (blockIdx.x & 3) * 64;
    const int rr = t >> 4, cc = (t & 15) * 4;
#pragma unroll
    for (int i = 0; i < 4; ++i) {
      float4 v = *(const float4*)&src[(size_t)(tr + rr + 16 * i) * 256 + tc + cc];
      tile[cc + 0][rr + 16 * i] = v.x;
      tile[cc + 1][rr + 16 * i] = v.y;
      tile[cc + 2][rr + 16 * i] = v.z;
      tile[cc + 3][rr + 16 * i] = v.w;
    }
    __syncthreads();
#pragma unroll
    for (int rnd = 0; rnd < 2; ++rnd) {
      const int u = rnd * 256 + t;
      const int nl = u >> 3, kl = (u & 7) * 8;
      if (m < 2) {
        const float sc = (m == 0) ? 0.25503488f : 1.0f;  // scale*log2e
        bf16x8 hv;
#pragma unroll
        for (int j = 0; j < 8; ++j) hv[j] = (short)f2bf(tile[nl][kl + j] * sc);
        ushort_t* dst = (m == 0) ? wqt : wot;
        *(bf16x8*)&dst[(size_t)(tc + nl) * 256 + tr + kl] = hv;
      } else {
        f16x8 hv;
#pragma unroll
        for (int j = 0; j < 8; ++j) hv[j] = (_Float16)tile[nl][kl + j];
        _Float16* dst = (m == 2) ? wkt : wvt;
        *(f16x8*)&dst[(size_t)(tc + nl) * 256 + tr + kl] = hv;
      }
    }
  }
}

// ---------------------------------------------------------------------------
// L2: merged qgemm (bid<512) + etx2 (bid>=512, splitK16). grid 640, 256 thr.
__global__ __launch_bounds__(256, 3) void k_mega1(
    const float* __restrict__ x1, const _Float16* __restrict__ xt,
    const ushort_t* __restrict__ wqt, ushort_t* __restrict__ Qf,
    _Float16* __restrict__ part16) {
  __shared__ __align__(16) char smem[32768];
  const int t = threadIdx.x;
  const int wv = t >> 6, ln = t & 63;
  const int l15 = ln & 15, g = ln >> 4;

  if (blockIdx.x < 512) {
    // ---------------- qgemm: Qf = x1 @ wqt^T (B-frag layout) ----------------
    ushort_t* wstage = (ushort_t*)smem;
    const size_t r0 = (size_t)blockIdx.x * 64;
    auto stage = [&](int row0, int colu, int buf) {
#pragma unroll
      for (int rnd = 0; rnd < 2; ++rnd) {
        const int u = rnd * 256 + wv * 64 + ln;
        const int row = STAGE_ROW(u);
        const int gg = STAGE_G(u);
        GLDS(wqt + (size_t)(row0 + row) * 256 + colu + gg * 8,
             &wstage[(buf * 512 + rnd * 256 + wv * 64) * 8]);
      }
    };
    f32x4 qacc[16];
#pragma unroll
    for (int i = 0; i < 16; ++i) qacc[i] = {0.f, 0.f, 0.f, 0.f};
    stage(0, 0, 0);
    const float* xrow = x1 + (r0 + wv * 16 + l15) * 256;
    float4 xa = *(const float4*)(xrow + g * 8);
    float4 xb = *(const float4*)(xrow + g * 8 + 4);
    __syncthreads();
    for (int ci = 0; ci < 16; ++ci) {
      const int nh = ci & 1;
      if (ci < 15) stage(((ci + 1) & 1) * 128, ((ci + 1) >> 1) * 32, (ci + 1) & 1);
      union { uint32_t u[4]; bf16x8 v; } af;
      af.u[0] = cvt_pk_bf16(xa.x, xa.y);
      af.u[1] = cvt_pk_bf16(xa.z, xa.w);
      af.u[2] = cvt_pk_bf16(xb.x, xb.y);
      af.u[3] = cvt_pk_bf16(xb.z, xb.w);
      const bf16x8 afrag = af.v;
      const ushort_t* cw = &wstage[(ci & 1) * 4096];
#pragma unroll
      for (int tt = 0; tt < 8; ++tt) {
        bf16x8 bfr = *(const bf16x8*)&cw[((tt * 16 + l15) * 32 + g * 8) ^
                                         ((l15 & 7) << 3)];
        qacc[nh * 8 + tt] = MFMA(afrag, bfr, qacc[nh * 8 + tt]);
      }
      if (nh == 1 && ci < 15) {
        int ks = (ci >> 1) + 1;
        xa = *(const float4*)(xrow + ks * 32 + g * 8);
        xb = *(const float4*)(xrow + ks * 32 + g * 8 + 4);
      }
      __syncthreads();
    }
    char* myq = smem + wv * 8192;
#pragma unroll
    for (int tt = 0; tt < 16; ++tt)
#pragma unroll
      for (int r = 0; r < 4; ++r) {
        const int gr = g * 4 + r;
        *(ushort_t*)(myq + gr * 512 + (((tt * 16 + l15) * 2) ^ ((gr & 7) << 4))) =
            f2bf(qacc[tt][r]);
      }
    __builtin_amdgcn_sched_barrier(0);
    const int rt = blockIdx.x * 4 + wv;
#pragma unroll
    for (int hh = 0; hh < 8; ++hh) {
      bf16x8 qf = *(const bf16x8*)(myq + l15 * 512 +
                                   ((hh * 64 + g * 16) ^ ((l15 & 7) << 4)));
      *(bf16x8*)&Qf[((size_t)(rt * 8 + hh) * 64 + ln) * 8] = qf;
    }
  } else {
    // ---------------- etx2: part16 = E^T x2 / F^T x2 (splitK 16) ------------
    const int bid = blockIdx.x - 512;  // 0..127
    const int which = bid & 1;
    const int chunk = (bid >> 1) & 15;
    const int quad = bid >> 5;  // 0..3
    const int kp0 = (quad >> 1) * 128;
    const int d0 = (quad & 1) * 128;
    const int n0 = chunk * 512;
    const _Float16* __restrict__ A = xt + (size_t)(1 + which) * 2097152;
    const _Float16* __restrict__ B = xt;
    const int wr = wv >> 1, wc = wv & 1;
    f32x4 acc[4][4];
#pragma unroll
    for (int i = 0; i < 4; ++i)
#pragma unroll
      for (int j = 0; j < 4; ++j) acc[i][j] = {0.f, 0.f, 0.f, 0.f};

    for (int ks = 0; ks < 8; ++ks) {
#pragma unroll
      for (int r8 = 0; r8 < 8; ++r8) {
        const int u = r8 * 256 + t;      // 0..2047 16B units
        const int mm = u >> 10;          // 0:A 1:B
        const int uu = u & 1023;
        const int row = uu >> 3;
        const int nsw = ((uu ^ row) & 7) << 3;  // source-swizzled n-elems
        const _Float16* gs =
            (mm ? B + (size_t)(d0 + row) * 8192
                : A + (size_t)(kp0 + row) * 8192) +
            n0 + ks * 64 + nsw;
        GLDS(gs, smem + (u & ~63) * 16);
      }
      __syncthreads();
      const char* la = smem;
      const char* lb = smem + 16384;
#pragma unroll
      for (int kk = 0; kk < 2; ++kk) {
        f16x8 af[4], bf[4];
#pragma unroll
        for (int i = 0; i < 4; ++i) {
          const int ra = wr * 64 + i * 16 + l15;
          af[i] = *(const f16x8*)(la + ra * 128 +
                                  ((kk * 64 + g * 16) ^ ((ra & 7) << 4)));
        }
#pragma unroll
        for (int j = 0; j < 4; ++j) {
          const int rb = wc * 64 + j * 16 + l15;
          bf[j] = *(const f16x8*)(lb + rb * 128 +
                                  ((kk * 64 + g * 16) ^ ((rb & 7) << 4)));
        }
#pragma unroll
        for (int i = 0; i < 4; ++i)
#pragma unroll
          for (int j = 0; j < 4; ++j)
            acc[i][j] = MFMA_H(af[i], bf[j], acc[i][j]);
      }
      __syncthreads();
    }
    _Float16* __restrict__ p = part16 + ((size_t)which * 16 + chunk) * 65536;
#pragma unroll
    for (int i = 0; i < 4; ++i)
#pragma unroll
      for (int j = 0; j < 4; ++j)
#pragma unroll
        for (int r = 0; r < 4; ++r)
          p[(size_t)(kp0 + wr * 64 + i * 16 + g * 4 + r) * 256 + d0 + wc * 64 +
            j * 16 + l15] = (_Float16)acc[i][j][r];
  }
}

// ---------------------------------------------------------------------------
// L3: reduce 16 fp16 partials (f32 accum) -> ghh fp16 [2][65536]. grid 512.
__global__ __launch_bounds__(256) void k_reduce_part(
    const _Float16* __restrict__ part16, _Float16* __restrict__ ghh) {
  const int oid = blockIdx.x * 256 + threadIdx.x;
  const int which = oid >> 16;
  const int base = oid & 65535;
  const _Float16* __restrict__ p = part16 + (size_t)which * 16 * 65536 + base;
  float s = 0.f;
#pragma unroll
  for (int c = 0; c < 16; ++c) s += (float)p[c * 65536];
  ghh[oid] = (_Float16)s;
}

// ---------------------------------------------------------------------------
// L4: klow/vlow proj + direct klowA/vtb epilogue. grid (4,2). (unchanged)
__global__ __launch_bounds__(256, 4) void k_lowproj2(
    const _Float16* __restrict__ ghh, const _Float16* __restrict__ wkt,
    const _Float16* __restrict__ wvt, ushort_t* __restrict__ klowA,
    ushort_t* __restrict__ vtb) {
  __shared__ __align__(16) _Float16 wstage[2][4096];
  const int t = threadIdx.x;
  const int wv = t >> 6, ln = t & 63;
  const int l15 = ln & 15, g = ln >> 4;
  const int which = blockIdx.y;
  const int r0 = blockIdx.x * 64;
  const _Float16* __restrict__ A = ghh + (size_t)which * 65536;
  const _Float16* __restrict__ W = which ? wvt : wkt;

  auto stage = [&](int row0, int colu, int buf) {
#pragma unroll
    for (int rnd = 0; rnd < 2; ++rnd) {
      const int u = rnd * 256 + wv * 64 + ln;
      const int row = STAGE_ROW(u);
      const int gg = STAGE_G(u);
      GLDS(W + (size_t)(row0 + row) * 256 + colu + gg * 8,
           &wstage[buf][(rnd * 256 + wv * 64) * 8]);
    }
  };

  f32x4 yacc[16];
#pragma unroll
  for (int i = 0; i < 16; ++i) yacc[i] = {0.f, 0.f, 0.f, 0.f};
  stage(0, 0, 0);
  const _Float16* arow = A + (size_t)(r0 + wv * 16 + l15) * 256;
  __syncthreads();
  for (int ci = 0; ci < 16; ++ci) {
    const int nh = ci & 1, ks = ci >> 1;
    if (ci < 15) stage(((ci + 1) & 1) * 128, ((ci + 1) >> 1) * 32, (ci + 1) & 1);
    f16x8 afrag = *(const f16x8*)(arow + ks * 32 + g * 8);
    const _Float16* cw = wstage[ci & 1];
#pragma unroll
    for (int tt = 0; tt < 8; ++tt) {
      f16x8 bfr = *(const f16x8*)&cw[((tt * 16 + l15) * 32 + g * 8) ^
                                     ((l15 & 7) << 3)];
      yacc[nh * 8 + tt] = MFMA_H(afrag, bfr, yacc[nh * 8 + tt]);
    }
    __syncthreads();
  }
#pragma unroll
  for (int tt = 0; tt < 16; ++tt)
#pragma unroll
    for (int r = 0; r < 4; ++r) {
      const int rowi = r0 + wv * 16 + g * 4 + r;
      const int c = tt * 16 + l15;
      const int hh = c >> 5, d = c & 31;
      const ushort_t val = f2bf(yacc[tt][r]);
      if (which == 0) {
        klowA[(hh << 13) + ((((rowi & 255) << 5) | d) ^ ((rowi & 7) << 3))] = val;
      } else {
        const int kh = (rowi >> 7) & 1, kl = rowi & 127;
        vtb[(((hh * 2 + kh) * 32 + d) << 7) + (kl ^ ((d & 7) << 3))] = val;
      }
    }
}

// ---------------------------------------------------------------------------
// L5: attention. grid (128 tiles of 256 rows, 8 heads), 512 thr. (unchanged)
__global__ __launch_bounds__(512, 4) void k_attn(
    const ushort_t* __restrict__ Qf, const ushort_t* __restrict__ klowA,
    const ushort_t* __restrict__ vtb, ushort_t* __restrict__ O) {
  __shared__ __align__(16) ushort_t kv[16384];  // klow 8192u | vt 8192u
  __shared__ __align__(16) uint32_t p_buf[8][320];
  __shared__ __align__(16) ushort_t o_sl[8][640];
  const int t = threadIdx.x;
  const int wv = t >> 6, ln = t & 63;
  const int l15 = ln & 15, g = ln >> 4;
  const int h = blockIdx.y;
  const size_t r0 = (size_t)blockIdx.x * 256;

  {  // stage one head's klowA + vtb (32 KB), pre-swizzled -> linear
    const ushort_t* ksrc = klowA + h * 8192;
    const ushort_t* vsrc = vtb + h * 8192;
#pragma unroll
    for (int rnd = 0; rnd < 2; ++rnd) {
      const int ub = rnd * 512 + wv * 64;
      GLDS(ksrc + (ub + ln) * 8, &kv[ub * 8]);
    }
#pragma unroll
    for (int rnd = 0; rnd < 2; ++rnd) {
      const int ub = rnd * 512 + wv * 64;
      GLDS(vsrc + (ub + ln) * 8, &kv[8192 + ub * 8]);
    }
  }
  const int rtb = blockIdx.x * 16 + wv;
  bf16x8 qfA = *(const bf16x8*)&Qf[((size_t)(rtb * 8 + h) * 64 + ln) * 8];
  bf16x8 qfB = *(const bf16x8*)&Qf[((size_t)((rtb + 8) * 8 + h) * 64 + ln) * 8];
  __syncthreads();

#pragma unroll
  for (int st = 0; st < 2; ++st) {
    const bf16x8 qfrag = st ? qfB : qfA;
    // scores: St = mfma(klow, Q)
    f32x4 s[16];
#pragma unroll
    for (int tt = 0; tt < 16; ++tt) {
      bf16x8 kfr = *(const bf16x8*)&kv[((tt * 16 + l15) * 32 + g * 8) ^
                                       ((l15 & 7) << 3)];
      f32x4 z = {0.f, 0.f, 0.f, 0.f};
      s[tt] = MFMA(kfr, qfrag, z);
    }
    // exp2-domain softmax (no max-subtract; log2e*scale folded into Wq)
    float sum = 0.f;
    uint32_t pw[16][2];
#pragma unroll
    for (int tt = 0; tt < 16; ++tt) {
      float e0 = exp2f(s[tt][0]), e1 = exp2f(s[tt][1]);
      float e2 = exp2f(s[tt][2]), e3 = exp2f(s[tt][3]);
      sum += (e0 + e1) + (e2 + e3);
      pw[tt][0] = cvt_pk_bf16(e0, e1);
      pw[tt][1] = cvt_pk_bf16(e2, e3);
    }
    sum += __shfl_xor(sum, 16);
    sum += __shfl_xor(sum, 32);
    const float rinv = 1.0f / sum;
    float rv[4];
#pragma unroll
    for (int r = 0; r < 4; ++r) rv[r] = __shfl(rinv, g * 4 + r);

    // PV via per-wave p_buf repack (b64 writes)
    f32x4 oacc[2];
    oacc[0] = {0.f, 0.f, 0.f, 0.f};
    oacc[1] = {0.f, 0.f, 0.f, 0.f};
    uint32_t* pbw = &p_buf[wv][l15 * 20];
#pragma unroll
    for (int kh = 0; kh < 2; ++kh) {
      const char* cv = (const char*)&kv[8192 + kh * 4096];
#pragma unroll
      for (int ksl = 0; ksl < 4; ++ksl) {
        const int ks = kh * 4 + ksl;
        uint2 w0, w1;
        w0.x = pw[2 * ks][0];     w0.y = pw[2 * ks][1];
        w1.x = pw[2 * ks + 1][0]; w1.y = pw[2 * ks + 1][1];
        *(uint2*)&pbw[2 * g] = w0;
        *(uint2*)&pbw[8 + 2 * g] = w1;
        __builtin_amdgcn_sched_barrier(0);
        bf16x8 pfr = *(const bf16x8*)&p_buf[wv][l15 * 20 + 4 * g];
#pragma unroll
        for (int nt = 0; nt < 2; ++nt) {
          bf16x8 vfr = *(const bf16x8*)(cv + (nt * 16 + l15) * 256 +
                                        ((ksl * 64 + g * 16) ^ ((l15 & 7) << 4)));
          oacc[nt] = MFMA(pfr, vfr, oacc[nt]);
        }
        __builtin_amdgcn_sched_barrier(0);
      }
    }
    // O write via per-wave repack (bf16, coalesced 16B stores)
#pragma unroll
    for (int nt = 0; nt < 2; ++nt)
#pragma unroll
      for (int r = 0; r < 4; ++r)
        o_sl[wv][(g * 4 + r) * 40 + nt * 16 + l15] = f2bf(oacc[nt][r] * rv[r]);
    __builtin_amdgcn_sched_barrier(0);
    {
      const int qr = ln >> 2, d0 = (ln & 3) * 8;
      bf16x8 ov = *(const bf16x8*)&o_sl[wv][qr * 40 + d0];
      *(bf16x8*)&O[(r0 + st * 128 + wv * 16 + qr) * 256 + h * 32 + d0] = ov;
    }
    __builtin_amdgcn_sched_barrier(0);
  }
}

// ---------------------------------------------------------------------------
// L6: out = O @ wot^T (f32). grid 512, 256 thr. (unchanged)
__global__ __launch_bounds__(256, 4) void k_ogemm(
    const ushort_t* __restrict__ O, const ushort_t* __restrict__ wot,
    float* __restrict__ out) {
  __shared__ __align__(16) ushort_t wstage[2][4096];
  const int t = threadIdx.x;
  const int wv = t >> 6, ln = t & 63;
  const int l15 = ln & 15, g = ln >> 4;
  const size_t r0 = (size_t)blockIdx.x * 64;

  auto stage = [&](int row0, int colu, int buf) {
#pragma unroll
    for (int rnd = 0; rnd < 2; ++rnd) {
      const int u = rnd * 256 + wv * 64 + ln;
      const int row = STAGE_ROW(u);
      const int gg = STAGE_G(u);
      GLDS(wot + (size_t)(row0 + row) * 256 + colu + gg * 8,
           &wstage[buf][(rnd * 256 + wv * 64) * 8]);
    }
  };

  f32x4 yacc[16];
#pragma unroll
  for (int i = 0; i < 16; ++i) yacc[i] = {0.f, 0.f, 0.f, 0.f};
  stage(0, 0, 0);
  const ushort_t* arow = O + (r0 + wv * 16 + l15) * 256;
  __syncthreads();
  for (int ci = 0; ci < 16; ++ci) {
    const int nh = ci & 1, ks = ci >> 1;
    if (ci < 15) stage(((ci + 1) & 1) * 128, ((ci + 1) >> 1) * 32, (ci + 1) & 1);
    bf16x8 afrag = *(const bf16x8*)(arow + ks * 32 + g * 8);
    const ushort_t* cw = wstage[ci & 1];
#pragma unroll
    for (int tt = 0; tt < 8; ++tt) {
      bf16x8 bfr = *(const bf16x8*)&cw[((tt * 16 + l15) * 32 + g * 8) ^
                                       ((l15 & 7) << 3)];
      yacc[nh * 8 + tt] = MFMA(afrag, bfr, yacc[nh * 8 + tt]);
    }
    __syncthreads();
  }
#pragma unroll
  for (int tt = 0; tt < 16; ++tt)
#pragma unroll
    for (int r = 0; r < 4; ++r)
      out[(r0 + wv * 16 + g * 4 + r) * 256 + tt * 16 + l15] = yacc[tt][r];
}

extern "C" void kernel_launch(void* const* d_in, const int* in_sizes, int n_in,
                              void* d_out, int out_size, void* d_ws, size_t ws_size,
                              hipStream_t stream) {
  const float* x1 = (const float*)d_in[0];
  const float* x2 = (const float*)d_in[1];
  const float* Wq = (const float*)d_in[2];
  const float* Wk = (const float*)d_in[3];
  const float* Wv = (const float*)d_in[4];
  const float* Wo = (const float*)d_in[5];
  const float* E  = (const float*)d_in[6];
  const float* F  = (const float*)d_in[7];
  float* out = (float*)d_out;
  float* ws = (float*)d_ws;
  // ws layout (float offsets):
  //  ghh fp16 @0 (65536) | wqt @65536 | wot @98304 | wkt @131072 | wvt @163840
  //  klowA @196608 | vtb @229376 | part16 fp16 @262144 (1,048,576 floats)
  //  Qf bf16 @2359296 (4,194,304) | xt fp16 @6553600 (3,145,728)
  //  O bf16 @6553600 overlays xt (xt dead after L2)
  _Float16* ghh = (_Float16*)ws;
  ushort_t* wqt = (ushort_t*)(ws + 65536);
  ushort_t* wot = (ushort_t*)(ws + 98304);
  _Float16* wkt = (_Float16*)(ws + 131072);
  _Float16* wvt = (_Float16*)(ws + 163840);
  ushort_t* klowA = (ushort_t*)(ws + 196608);
  ushort_t* vtb = (ushort_t*)(ws + 229376);
  _Float16* part16 = (_Float16*)(ws + 262144);
  ushort_t* Qf = (ushort_t*)(ws + 2359296);
  _Float16* xt = (_Float16*)(ws + 6553600);
  ushort_t* O = (ushort_t*)(ws + 6553600);

  k_prep_all<<<dim3(128, 4, 4), 256, 0, stream>>>(x2, E, F, Wq, Wk, Wv, Wo, xt,
                                                  wqt, wot, wkt, wvt);
  k_mega1<<<640, 256, 0, stream>>>(x1, xt, wqt, Qf, part16);
  k_reduce_part<<<512, 256, 0, stream>>>(part16, ghh);
  k_lowproj2<<<dim3(4, 2), 256, 0, stream>>>(ghh, wkt, wvt, klowA, vtb);
  k_attn<<<dim3(128, 8), 512, 0, stream>>>(Qf, klowA, vtb, O);
  k_ogemm<<<512, 256, 0, stream>>>(O, wot, out);
}

// Round 16
// 83.383 us; speedup vs baseline: 1.4614x; 1.0010x over previous
//
#include <hip/hip_runtime.h>
#include <math.h>
#include <stdint.h>

// B=4, NQ=8192, NKV=8192, D=256, H=8, HD=32, KP=256. ROWS = 32768.
// CONVERGED STATE (83.5 us): round-9 structure + cvt_pk packing (T12) +
// ds_write_b64 p_buf + fp16 split-K partials. See round 15 post-mortem:
// all remaining structural levers measured and refuted (r6,r8,r10-r13).
// L1 k_prep_all: x2,E,F -> xt fp16 [3][256][8192] (transposed); W transposes
// L2 k_mega1:    qgemm (512 blks): Qf = x1@Wq^T (B-frag layout)
//                + etx2 (128 blks): part16 = E^T x2 / F^T x2 (fp16 MFMA sK16)
// L3 k_reduce:   sum 16 fp16 partials (f32 accum) -> ghh fp16 (512 blks)
// L4 k_lowproj2: klow=G@Wk, vlow=Hh@Wv (fp16 MFMA) -> klowA/vtb direct
// L5 k_attn:     per (256-row tile, head): St=mfma(klow,Q), exp2 softmax,
//                PV -> O bf16 (2 row-subtiles per staged KV)
// L6 k_ogemm:    out = O @ Wo^T (f32)

typedef unsigned short ushort_t;
typedef __attribute__((ext_vector_type(8))) short bf16x8;
typedef __attribute__((ext_vector_type(8))) _Float16 f16x8;
typedef __attribute__((ext_vector_type(4))) float f32x4;

__device__ __forceinline__ f32x4 MFMA(bf16x8 a, bf16x8 b, f32x4 c) {
  return __builtin_amdgcn_mfma_f32_16x16x32_bf16(a, b, c, 0, 0, 0);
}
__device__ __forceinline__ f32x4 MFMA_H(f16x8 a, f16x8 b, f32x4 c) {
  return __builtin_amdgcn_mfma_f32_16x16x32_f16(a, b, c, 0, 0, 0);
}
__device__ __forceinline__ ushort_t f2bf(float x) {
  uint32_t u = __float_as_uint(x);
  u += 0x7fffu + ((u >> 16) & 1u);
  return (ushort_t)(u >> 16);
}
// packed f32 pair -> bf16x2 in one VALU op (lo = a, hi = b)
__device__ __forceinline__ uint32_t cvt_pk_bf16(float a, float b) {
  uint32_t r;
  asm("v_cvt_pk_bf16_f32 %0, %1, %2" : "=v"(r) : "v"(a), "v"(b));
  return r;
}
#define GLDS(gsrc, ldst)                                                    \
  __builtin_amdgcn_global_load_lds(                                         \
      (const __attribute__((address_space(1))) uint32_t*)(const void*)(gsrc), \
      (__attribute__((address_space(3))) uint32_t*)(void*)(ldst), 16, 0, 0)

// 3-bit XOR chunk staging helpers (proven rounds 3-15)
#define STAGE_ROW(u) \
  (((((u) >> 2) ^ ((u) >> 4)) & 1) | (((u) >> 2) & 6) | (((u) >> 5) << 3))
#define STAGE_G(u) \
  ((((u) ^ ((u) >> 2) ^ ((u) >> 4)) & 1) | (((((u) >> 1) ^ ((u) >> 3)) & 1) << 1))

// ---------------------------------------------------------------------------
// L1: transposes. grid (128,4,4), 256 thr.
__global__ __launch_bounds__(256) void k_prep_all(
    const float* __restrict__ x2, const float* __restrict__ E,
    const float* __restrict__ F, const float* __restrict__ Wq,
    const float* __restrict__ Wk, const float* __restrict__ Wv,
    const float* __restrict__ Wo, _Float16* __restrict__ xt,
    ushort_t* __restrict__ wqt, ushort_t* __restrict__ wot,
    _Float16* __restrict__ wkt, _Float16* __restrict__ wvt) {
  __shared__ float tile[64][65];
  const int t = threadIdx.x;
  const int z = blockIdx.z;
  if (z < 3) {
    const int n0 = blockIdx.x * 64;
    const int c0 = blockIdx.y * 64;
    const float* __restrict__ src = (z == 0) ? x2 : (z == 1) ? E : F;
    _Float16* __restrict__ dst = xt + (size_t)z * 2097152;
    const int rr = t >> 4, cc = (t & 15) * 4;
#pragma unroll
    for (int i = 0; i < 4; ++i) {
      float4 v = *(const float4*)&src[(size_t)(n0 + rr + 16 * i) * 256 + c0 + cc];
      tile[cc + 0][rr + 16 * i] = v.x;
      tile[cc + 1][rr + 16 * i] = v.y;
      tile[cc + 2][rr + 16 * i] = v.z;
      tile[cc + 3][rr + 16 * i] = v.w;
    }
    __syncthreads();
#pragma unroll
    for (int rnd = 0; rnd < 2; ++rnd) {
      const int u = rnd * 256 + t;
      const int c = u >> 3, r0 = (u & 7) * 8;
      f16x8 h;
#pragma unroll
      for (int j = 0; j < 8; ++j) h[j] = (_Float16)tile[c][r0 + j];
      *(f16x8*)&dst[(size_t)(c0 + c) * 8192 + n0 + r0] = h;
    }
  } else {
    if (blockIdx.x >= 16) return;
    const int m = blockIdx.y;
    const float* __restrict__ src = (m == 0) ? Wq : (m == 1) ? Wo
                                  : (m == 2) ? Wk : Wv;
    const int tr = (blockIdx.x >> 2) * 64;
    const int tc = (blockIdx.x & 3) * 64;
    const int rr = t >> 4, cc = (t & 15) * 4;
#pragma unroll
    for (int i = 0; i < 4; ++i) {
      float4 v = *(const float4*)&src[(size_t)(tr + rr + 16 * i) * 256 + tc + cc];
      tile[cc + 0][rr + 16 * i] = v.x;
      tile[cc + 1][rr + 16 * i] = v.y;
      tile[cc + 2][rr + 16 * i] = v.z;
      tile[cc + 3][rr + 16 * i] = v.w;
    }
    __syncthreads();
#pragma unroll
    for (int rnd = 0; rnd < 2; ++rnd) {
      const int u = rnd * 256 + t;
      const int nl = u >> 3, kl = (u & 7) * 8;
      if (m < 2) {
        const float sc = (m == 0) ? 0.25503488f : 1.0f;  // scale*log2e
        bf16x8 hv;
#pragma unroll
        for (int j = 0; j < 8; ++j) hv[j] = (short)f2bf(tile[nl][kl + j] * sc);
        ushort_t* dst = (m == 0) ? wqt : wot;
        *(bf16x8*)&dst[(size_t)(tc + nl) * 256 + tr + kl] = hv;
      } else {
        f16x8 hv;
#pragma unroll
        for (int j = 0; j < 8; ++j) hv[j] = (_Float16)tile[nl][kl + j];
        _Float16* dst = (m == 2) ? wkt : wvt;
        *(f16x8*)&dst[(size_t)(tc + nl) * 256 + tr + kl] = hv;
      }
    }
  }
}

// ---------------------------------------------------------------------------
// L2: merged qgemm (bid<512) + etx2 (bid>=512, splitK16). grid 640, 256 thr.
__global__ __launch_bounds__(256, 3) void k_mega1(
    const float* __restrict__ x1, const _Float16* __restrict__ xt,
    const ushort_t* __restrict__ wqt, ushort_t* __restrict__ Qf,
    _Float16* __restrict__ part16) {
  __shared__ __align__(16) char smem[32768];
  const int t = threadIdx.x;
  const int wv = t >> 6, ln = t & 63;
  const int l15 = ln & 15, g = ln >> 4;

  if (blockIdx.x < 512) {
    // ---------------- qgemm: Qf = x1 @ wqt^T (B-frag layout) ----------------
    ushort_t* wstage = (ushort_t*)smem;
    const size_t r0 = (size_t)blockIdx.x * 64;
    auto stage = [&](int row0, int colu, int buf) {
#pragma unroll
      for (int rnd = 0; rnd < 2; ++rnd) {
        const int u = rnd * 256 + wv * 64 + ln;
        const int row = STAGE_ROW(u);
        const int gg = STAGE_G(u);
        GLDS(wqt + (size_t)(row0 + row) * 256 + colu + gg * 8,
             &wstage[(buf * 512 + rnd * 256 + wv * 64) * 8]);
      }
    };
    f32x4 qacc[16];
#pragma unroll
    for (int i = 0; i < 16; ++i) qacc[i] = {0.f, 0.f, 0.f, 0.f};
    stage(0, 0, 0);
    const float* xrow = x1 + (r0 + wv * 16 + l15) * 256;
    float4 xa = *(const float4*)(xrow + g * 8);
    float4 xb = *(const float4*)(xrow + g * 8 + 4);
    __syncthreads();
    for (int ci = 0; ci < 16; ++ci) {
      const int nh = ci & 1;
      if (ci < 15) stage(((ci + 1) & 1) * 128, ((ci + 1) >> 1) * 32, (ci + 1) & 1);
      union { uint32_t u[4]; bf16x8 v; } af;
      af.u[0] = cvt_pk_bf16(xa.x, xa.y);
      af.u[1] = cvt_pk_bf16(xa.z, xa.w);
      af.u[2] = cvt_pk_bf16(xb.x, xb.y);
      af.u[3] = cvt_pk_bf16(xb.z, xb.w);
      const bf16x8 afrag = af.v;
      const ushort_t* cw = &wstage[(ci & 1) * 4096];
#pragma unroll
      for (int tt = 0; tt < 8; ++tt) {
        bf16x8 bfr = *(const bf16x8*)&cw[((tt * 16 + l15) * 32 + g * 8) ^
                                         ((l15 & 7) << 3)];
        qacc[nh * 8 + tt] = MFMA(afrag, bfr, qacc[nh * 8 + tt]);
      }
      if (nh == 1 && ci < 15) {
        int ks = (ci >> 1) + 1;
        xa = *(const float4*)(xrow + ks * 32 + g * 8);
        xb = *(const float4*)(xrow + ks * 32 + g * 8 + 4);
      }
      __syncthreads();
    }
    char* myq = smem + wv * 8192;
#pragma unroll
    for (int tt = 0; tt < 16; ++tt)
#pragma unroll
      for (int r = 0; r < 4; ++r) {
        const int gr = g * 4 + r;
        *(ushort_t*)(myq + gr * 512 + (((tt * 16 + l15) * 2) ^ ((gr & 7) << 4))) =
            f2bf(qacc[tt][r]);
      }
    __builtin_amdgcn_sched_barrier(0);
    const int rt = blockIdx.x * 4 + wv;
#pragma unroll
    for (int hh = 0; hh < 8; ++hh) {
      bf16x8 qf = *(const bf16x8*)(myq + l15 * 512 +
                                   ((hh * 64 + g * 16) ^ ((l15 & 7) << 4)));
      *(bf16x8*)&Qf[((size_t)(rt * 8 + hh) * 64 + ln) * 8] = qf;
    }
  } else {
    // ---------------- etx2: part16 = E^T x2 / F^T x2 (splitK 16) ------------
    const int bid = blockIdx.x - 512;  // 0..127
    const int which = bid & 1;
    const int chunk = (bid >> 1) & 15;
    const int quad = bid >> 5;  // 0..3
    const int kp0 = (quad >> 1) * 128;
    const int d0 = (quad & 1) * 128;
    const int n0 = chunk * 512;
    const _Float16* __restrict__ A = xt + (size_t)(1 + which) * 2097152;
    const _Float16* __restrict__ B = xt;
    const int wr = wv >> 1, wc = wv & 1;
    f32x4 acc[4][4];
#pragma unroll
    for (int i = 0; i < 4; ++i)
#pragma unroll
      for (int j = 0; j < 4; ++j) acc[i][j] = {0.f, 0.f, 0.f, 0.f};

    for (int ks = 0; ks < 8; ++ks) {
#pragma unroll
      for (int r8 = 0; r8 < 8; ++r8) {
        const int u = r8 * 256 + t;      // 0..2047 16B units
        const int mm = u >> 10;          // 0:A 1:B
        const int uu = u & 1023;
        const int row = uu >> 3;
        const int nsw = ((uu ^ row) & 7) << 3;  // source-swizzled n-elems
        const _Float16* gs =
            (mm ? B + (size_t)(d0 + row) * 8192
                : A + (size_t)(kp0 + row) * 8192) +
            n0 + ks * 64 + nsw;
        GLDS(gs, smem + (u & ~63) * 16);
      }
      __syncthreads();
      const char* la = smem;
      const char* lb = smem + 16384;
#pragma unroll
      for (int kk = 0; kk < 2; ++kk) {
        f16x8 af[4], bf[4];
#pragma unroll
        for (int i = 0; i < 4; ++i) {
          const int ra = wr * 64 + i * 16 + l15;
          af[i] = *(const f16x8*)(la + ra * 128 +
                                  ((kk * 64 + g * 16) ^ ((ra & 7) << 4)));
        }
#pragma unroll
        for (int j = 0; j < 4; ++j) {
          const int rb = wc * 64 + j * 16 + l15;
          bf[j] = *(const f16x8*)(lb + rb * 128 +
                                  ((kk * 64 + g * 16) ^ ((rb & 7) << 4)));
        }
#pragma unroll
        for (int i = 0; i < 4; ++i)
#pragma unroll
          for (int j = 0; j < 4; ++j)
            acc[i][j] = MFMA_H(af[i], bf[j], acc[i][j]);
      }
      __syncthreads();
    }
    _Float16* __restrict__ p = part16 + ((size_t)which * 16 + chunk) * 65536;
#pragma unroll
    for (int i = 0; i < 4; ++i)
#pragma unroll
      for (int j = 0; j < 4; ++j)
#pragma unroll
        for (int r = 0; r < 4; ++r)
          p[(size_t)(kp0 + wr * 64 + i * 16 + g * 4 + r) * 256 + d0 + wc * 64 +
            j * 16 + l15] = (_Float16)acc[i][j][r];
  }
}

// ---------------------------------------------------------------------------
// L3: reduce 16 fp16 partials (f32 accum) -> ghh fp16 [2][65536]. grid 512.
__global__ __launch_bounds__(256) void k_reduce_part(
    const _Float16* __restrict__ part16, _Float16* __restrict__ ghh) {
  const int oid = blockIdx.x * 256 + threadIdx.x;
  const int which = oid >> 16;
  const int base = oid & 65535;
  const _Float16* __restrict__ p = part16 + (size_t)which * 16 * 65536 + base;
  float s = 0.f;
#pragma unroll
  for (int c = 0; c < 16; ++c) s += (float)p[c * 65536];
  ghh[oid] = (_Float16)s;
}

// ---------------------------------------------------------------------------
// L4: klow/vlow proj + direct klowA/vtb epilogue. grid (4,2).
__global__ __launch_bounds__(256, 4) void k_lowproj2(
    const _Float16* __restrict__ ghh, const _Float16* __restrict__ wkt,
    const _Float16* __restrict__ wvt, ushort_t* __restrict__ klowA,
    ushort_t* __restrict__ vtb) {
  __shared__ __align__(16) _Float16 wstage[2][4096];
  const int t = threadIdx.x;
  const int wv = t >> 6, ln = t & 63;
  const int l15 = ln & 15, g = ln >> 4;
  const int which = blockIdx.y;
  const int r0 = blockIdx.x * 64;
  const _Float16* __restrict__ A = ghh + (size_t)which * 65536;
  const _Float16* __restrict__ W = which ? wvt : wkt;

  auto stage = [&](int row0, int colu, int buf) {
#pragma unroll
    for (int rnd = 0; rnd < 2; ++rnd) {
      const int u = rnd * 256 + wv * 64 + ln;
      const int row = STAGE_ROW(u);
      const int gg = STAGE_G(u);
      GLDS(W + (size_t)(row0 + row) * 256 + colu + gg * 8,
           &wstage[buf][(rnd * 256 + wv * 64) * 8]);
    }
  };

  f32x4 yacc[16];
#pragma unroll
  for (int i = 0; i < 16; ++i) yacc[i] = {0.f, 0.f, 0.f, 0.f};
  stage(0, 0, 0);
  const _Float16* arow = A + (size_t)(r0 + wv * 16 + l15) * 256;
  __syncthreads();
  for (int ci = 0; ci < 16; ++ci) {
    const int nh = ci & 1, ks = ci >> 1;
    if (ci < 15) stage(((ci + 1) & 1) * 128, ((ci + 1) >> 1) * 32, (ci + 1) & 1);
    f16x8 afrag = *(const f16x8*)(arow + ks * 32 + g * 8);
    const _Float16* cw = wstage[ci & 1];
#pragma unroll
    for (int tt = 0; tt < 8; ++tt) {
      f16x8 bfr = *(const f16x8*)&cw[((tt * 16 + l15) * 32 + g * 8) ^
                                     ((l15 & 7) << 3)];
      yacc[nh * 8 + tt] = MFMA_H(afrag, bfr, yacc[nh * 8 + tt]);
    }
    __syncthreads();
  }
#pragma unroll
  for (int tt = 0; tt < 16; ++tt)
#pragma unroll
    for (int r = 0; r < 4; ++r) {
      const int rowi = r0 + wv * 16 + g * 4 + r;
      const int c = tt * 16 + l15;
      const int hh = c >> 5, d = c & 31;
      const ushort_t val = f2bf(yacc[tt][r]);
      if (which == 0) {
        klowA[(hh << 13) + ((((rowi & 255) << 5) | d) ^ ((rowi & 7) << 3))] = val;
      } else {
        const int kh = (rowi >> 7) & 1, kl = rowi & 127;
        vtb[(((hh * 2 + kh) * 32 + d) << 7) + (kl ^ ((d & 7) << 3))] = val;
      }
    }
}

// ---------------------------------------------------------------------------
// L5: attention. grid (128 tiles of 256 rows, 8 heads), 512 thr.
__global__ __launch_bounds__(512, 4) void k_attn(
    const ushort_t* __restrict__ Qf, const ushort_t* __restrict__ klowA,
    const ushort_t* __restrict__ vtb, ushort_t* __restrict__ O) {
  __shared__ __align__(16) ushort_t kv[16384];  // klow 8192u | vt 8192u
  __shared__ __align__(16) uint32_t p_buf[8][320];
  __shared__ __align__(16) ushort_t o_sl[8][640];
  const int t = threadIdx.x;
  const int wv = t >> 6, ln = t & 63;
  const int l15 = ln & 15, g = ln >> 4;
  const int h = blockIdx.y;
  const size_t r0 = (size_t)blockIdx.x * 256;

  {  // stage one head's klowA + vtb (32 KB), pre-swizzled -> linear
    const ushort_t* ksrc = klowA + h * 8192;
    const ushort_t* vsrc = vtb + h * 8192;
#pragma unroll
    for (int rnd = 0; rnd < 2; ++rnd) {
      const int ub = rnd * 512 + wv * 64;
      GLDS(ksrc + (ub + ln) * 8, &kv[ub * 8]);
    }
#pragma unroll
    for (int rnd = 0; rnd < 2; ++rnd) {
      const int ub = rnd * 512 + wv * 64;
      GLDS(vsrc + (ub + ln) * 8, &kv[8192 + ub * 8]);
    }
  }
  const int rtb = blockIdx.x * 16 + wv;
  bf16x8 qfA = *(const bf16x8*)&Qf[((size_t)(rtb * 8 + h) * 64 + ln) * 8];
  bf16x8 qfB = *(const bf16x8*)&Qf[((size_t)((rtb + 8) * 8 + h) * 64 + ln) * 8];
  __syncthreads();

#pragma unroll
  for (int st = 0; st < 2; ++st) {
    const bf16x8 qfrag = st ? qfB : qfA;
    // scores: St = mfma(klow, Q)
    f32x4 s[16];
#pragma unroll
    for (int tt = 0; tt < 16; ++tt) {
      bf16x8 kfr = *(const bf16x8*)&kv[((tt * 16 + l15) * 32 + g * 8) ^
                                       ((l15 & 7) << 3)];
      f32x4 z = {0.f, 0.f, 0.f, 0.f};
      s[tt] = MFMA(kfr, qfrag, z);
    }
    // exp2-domain softmax (no max-subtract; log2e*scale folded into Wq)
    float sum = 0.f;
    uint32_t pw[16][2];
#pragma unroll
    for (int tt = 0; tt < 16; ++tt) {
      float e0 = exp2f(s[tt][0]), e1 = exp2f(s[tt][1]);
      float e2 = exp2f(s[tt][2]), e3 = exp2f(s[tt][3]);
      sum += (e0 + e1) + (e2 + e3);
      pw[tt][0] = cvt_pk_bf16(e0, e1);
      pw[tt][1] = cvt_pk_bf16(e2, e3);
    }
    sum += __shfl_xor(sum, 16);
    sum += __shfl_xor(sum, 32);
    const float rinv = 1.0f / sum;
    float rv[4];
#pragma unroll
    for (int r = 0; r < 4; ++r) rv[r] = __shfl(rinv, g * 4 + r);

    // PV via per-wave p_buf repack (b64 writes)
    f32x4 oacc[2];
    oacc[0] = {0.f, 0.f, 0.f, 0.f};
    oacc[1] = {0.f, 0.f, 0.f, 0.f};
    uint32_t* pbw = &p_buf[wv][l15 * 20];
#pragma unroll
    for (int kh = 0; kh < 2; ++kh) {
      const char* cv = (const char*)&kv[8192 + kh * 4096];
#pragma unroll
      for (int ksl = 0; ksl < 4; ++ksl) {
        const int ks = kh * 4 + ksl;
        uint2 w0, w1;
        w0.x = pw[2 * ks][0];     w0.y = pw[2 * ks][1];
        w1.x = pw[2 * ks + 1][0]; w1.y = pw[2 * ks + 1][1];
        *(uint2*)&pbw[2 * g] = w0;
        *(uint2*)&pbw[8 + 2 * g] = w1;
        __builtin_amdgcn_sched_barrier(0);
        bf16x8 pfr = *(const bf16x8*)&p_buf[wv][l15 * 20 + 4 * g];
#pragma unroll
        for (int nt = 0; nt < 2; ++nt) {
          bf16x8 vfr = *(const bf16x8*)(cv + (nt * 16 + l15) * 256 +
                                        ((ksl * 64 + g * 16) ^ ((l15 & 7) << 4)));
          oacc[nt] = MFMA(pfr, vfr, oacc[nt]);
        }
        __builtin_amdgcn_sched_barrier(0);
      }
    }
    // O write via per-wave repack (bf16, coalesced 16B stores)
#pragma unroll
    for (int nt = 0; nt < 2; ++nt)
#pragma unroll
      for (int r = 0; r < 4; ++r)
        o_sl[wv][(g * 4 + r) * 40 + nt * 16 + l15] = f2bf(oacc[nt][r] * rv[r]);
    __builtin_amdgcn_sched_barrier(0);
    {
      const int qr = ln >> 2, d0 = (ln & 3) * 8;
      bf16x8 ov = *(const bf16x8*)&o_sl[wv][qr * 40 + d0];
      *(bf16x8*)&O[(r0 + st * 128 + wv * 16 + qr) * 256 + h * 32 + d0] = ov;
    }
    __builtin_amdgcn_sched_barrier(0);
  }
}

// ---------------------------------------------------------------------------
// L6: out = O @ wot^T (f32). grid 512, 256 thr.
__global__ __launch_bounds__(256, 4) void k_ogemm(
    const ushort_t* __restrict__ O, const ushort_t* __restrict__ wot,
    float* __restrict__ out) {
  __shared__ __align__(16) ushort_t wstage[2][4096];
  const int t = threadIdx.x;
  const int wv = t >> 6, ln = t & 63;
  const int l15 = ln & 15, g = ln >> 4;
  const size_t r0 = (size_t)blockIdx.x * 64;

  auto stage = [&](int row0, int colu, int buf) {
#pragma unroll
    for (int rnd = 0; rnd < 2; ++rnd) {
      const int u = rnd * 256 + wv * 64 + ln;
      const int row = STAGE_ROW(u);
      const int gg = STAGE_G(u);
      GLDS(wot + (size_t)(row0 + row) * 256 + colu + gg * 8,
           &wstage[buf][(rnd * 256 + wv * 64) * 8]);
    }
  };

  f32x4 yacc[16];
#pragma unroll
  for (int i = 0; i < 16; ++i) yacc[i] = {0.f, 0.f, 0.f, 0.f};
  stage(0, 0, 0);
  const ushort_t* arow = O + (r0 + wv * 16 + l15) * 256;
  __syncthreads();
  for (int ci = 0; ci < 16; ++ci) {
    const int nh = ci & 1, ks = ci >> 1;
    if (ci < 15) stage(((ci + 1) & 1) * 128, ((ci + 1) >> 1) * 32, (ci + 1) & 1);
    bf16x8 afrag = *(const bf16x8*)(arow + ks * 32 + g * 8);
    const ushort_t* cw = wstage[ci & 1];
#pragma unroll
    for (int tt = 0; tt < 8; ++tt) {
      bf16x8 bfr = *(const bf16x8*)&cw[((tt * 16 + l15) * 32 + g * 8) ^
                                       ((l15 & 7) << 3)];
      yacc[nh * 8 + tt] = MFMA(afrag, bfr, yacc[nh * 8 + tt]);
    }
    __syncthreads();
  }
#pragma unroll
  for (int tt = 0; tt < 16; ++tt)
#pragma unroll
    for (int r = 0; r < 4; ++r)
      out[(r0 + wv * 16 + g * 4 + r) * 256 + tt * 16 + l15] = yacc[tt][r];
}

extern "C" void kernel_launch(void* const* d_in, const int* in_sizes, int n_in,
                              void* d_out, int out_size, void* d_ws, size_t ws_size,
                              hipStream_t stream) {
  const float* x1 = (const float*)d_in[0];
  const float* x2 = (const float*)d_in[1];
  const float* Wq = (const float*)d_in[2];
  const float* Wk = (const float*)d_in[3];
  const float* Wv = (const float*)d_in[4];
  const float* Wo = (const float*)d_in[5];
  const float* E  = (const float*)d_in[6];
  const float* F  = (const float*)d_in[7];
  float* out = (float*)d_out;
  float* ws = (float*)d_ws;
  // ws layout (float offsets):
  //  ghh fp16 @0 (65536) | wqt @65536 | wot @98304 | wkt @131072 | wvt @163840
  //  klowA @196608 | vtb @229376 | part16 fp16 @262144 (1,048,576 floats)
  //  Qf bf16 @2359296 (4,194,304) | xt fp16 @6553600 (3,145,728)
  //  O bf16 @6553600 overlays xt (xt dead after L2)
  _Float16* ghh = (_Float16*)ws;
  ushort_t* wqt = (ushort_t*)(ws + 65536);
  ushort_t* wot = (ushort_t*)(ws + 98304);
  _Float16* wkt = (_Float16*)(ws + 131072);
  _Float16* wvt = (_Float16*)(ws + 163840);
  ushort_t* klowA = (ushort_t*)(ws + 196608);
  ushort_t* vtb = (ushort_t*)(ws + 229376);
  _Float16* part16 = (_Float16*)(ws + 262144);
  ushort_t* Qf = (ushort_t*)(ws + 2359296);
  _Float16* xt = (_Float16*)(ws + 6553600);
  ushort_t* O = (ushort_t*)(ws + 6553600);

  k_prep_all<<<dim3(128, 4, 4), 256, 0, stream>>>(x2, E, F, Wq, Wk, Wv, Wo, xt,
                                                  wqt, wot, wkt, wvt);
  k_mega1<<<640, 256, 0, stream>>>(x1, xt, wqt, Qf, part16);
  k_reduce_part<<<512, 256, 0, stream>>>(part16, ghh);
  k_lowproj2<<<dim3(4, 2), 256, 0, stream>>>(ghh, wkt, wvt, klowA, vtb);
  k_attn<<<dim3(128, 8), 512, 0, stream>>>(Qf, klowA, vtb, O);
  k_ogemm<<<512, 256, 0, stream>>>(O, wot, out);
}